// Round 1
// baseline (223.375 us; speedup 1.0000x reference)
//
#include <hip/hip_runtime.h>
#include <stdint.h>

#define L_SEQ 2048
#define HID   2048
#define NHEAD 32
#define NKV   8
#define HD    64
#define KVDIM 512

typedef __attribute__((ext_vector_type(8))) short s16x8;
typedef __attribute__((ext_vector_type(4))) short s16x4;
typedef __attribute__((ext_vector_type(4))) float f32x4;

__device__ __forceinline__ short f2bf(float f) {
  union { float f; uint32_t u; } v; v.f = f;
  uint32_t r = v.u + 0x7fffu + ((v.u >> 16) & 1u);
  return (short)(r >> 16);
}

// ---------------- weights f32 -> bf16 ----------------
__global__ __launch_bounds__(256) void convert_weights_kernel(
    const float* __restrict__ wq, const float* __restrict__ wk,
    const float* __restrict__ wv, const float* __restrict__ wo,
    short* __restrict__ owq, short* __restrict__ owk,
    short* __restrict__ owv, short* __restrict__ owo) {
  int64_t e = ((int64_t)blockIdx.x * 256 + threadIdx.x) * 4;
  const float* src; short* dst; int64_t o;
  if (e < 4194304)      { src = wq; dst = owq; o = e; }
  else if (e < 5242880) { src = wk; dst = owk; o = e - 4194304; }
  else if (e < 6291456) { src = wv; dst = owv; o = e - 5242880; }
  else                  { src = wo; dst = owo; o = e - 6291456; }
  f32x4 v = *(const f32x4*)(src + o);
  s16x4 b;
  b[0] = f2bf(v[0]); b[1] = f2bf(v[1]); b[2] = f2bf(v[2]); b[3] = f2bf(v[3]);
  *(s16x4*)(dst + o) = b;
}

// ---------------- RMSNorm (f32 in, bf16 out) ----------------
__global__ __launch_bounds__(256) void rmsnorm_kernel(
    const float* __restrict__ x, const float* __restrict__ w,
    short* __restrict__ h) {
  const int row = blockIdx.x, tid = threadIdx.x;
  const float* xr = x + (int64_t)row * HID + tid * 8;
  f32x4 a = *(const f32x4*)(xr);
  f32x4 b = *(const f32x4*)(xr + 4);
  float ss = a[0]*a[0]+a[1]*a[1]+a[2]*a[2]+a[3]*a[3]
           + b[0]*b[0]+b[1]*b[1]+b[2]*b[2]+b[3]*b[3];
  #pragma unroll
  for (int off = 1; off < 64; off <<= 1) ss += __shfl_xor(ss, off, 64);
  __shared__ float sred[4];
  if ((tid & 63) == 0) sred[tid >> 6] = ss;
  __syncthreads();
  const float scale = rsqrtf((sred[0]+sred[1]+sred[2]+sred[3]) * (1.0f/HID) + 1e-6f);
  const float* wp = w + tid * 8;
  f32x4 wa = *(const f32x4*)(wp);
  f32x4 wb = *(const f32x4*)(wp + 4);
  s16x8 o;
  o[0]=f2bf(a[0]*scale*wa[0]); o[1]=f2bf(a[1]*scale*wa[1]);
  o[2]=f2bf(a[2]*scale*wa[2]); o[3]=f2bf(a[3]*scale*wa[3]);
  o[4]=f2bf(b[0]*scale*wb[0]); o[5]=f2bf(b[1]*scale*wb[1]);
  o[6]=f2bf(b[2]*scale*wb[2]); o[7]=f2bf(b[3]*scale*wb[3]);
  *(s16x8*)(h + (int64_t)row * HID + tid * 8) = o;
}

// ---------------- GEMM core: C(128x128) = A(128xK) * B(128xK)^T, K=2048 ----
// A,B bf16 row-major, K-contiguous. XOR-swizzled LDS (T2) to keep
// ds_read_b128 conflict-free at 128B row stride.
__device__ __forceinline__ void gemm_core_128(
    const short* __restrict__ A, const short* __restrict__ B,
    short* sA, short* sB, f32x4 acc[4][4]) {
  const int tid = threadIdx.x;
  const int lane = tid & 63;
  const int w = tid >> 6, wr = w >> 1, wc = w & 1;
  const int g = lane >> 4, li = lane & 15;
  for (int k0 = 0; k0 < HID; k0 += 64) {
    #pragma unroll
    for (int i = 0; i < 4; ++i) {
      const int flat = i * 256 + tid;       // 0..1023, 16B chunks
      const int row = flat >> 3, c8 = flat & 7;
      const int slot = c8 ^ (row & 7);      // write-side swizzle
      s16x8 va = *(const s16x8*)(A + row * HID + k0 + c8 * 8);
      s16x8 vb = *(const s16x8*)(B + row * HID + k0 + c8 * 8);
      *(s16x8*)(sA + row * 64 + slot * 8) = va;
      *(s16x8*)(sB + row * 64 + slot * 8) = vb;
    }
    __syncthreads();
    #pragma unroll
    for (int kk = 0; kk < 2; ++kk) {
      s16x8 af[4], bfr[4];
      const int chunk = (kk << 2) | g;
      #pragma unroll
      for (int m = 0; m < 4; ++m) {
        const int row = wr * 64 + m * 16 + li;   // row&7 == li&7
        af[m] = *(const s16x8*)(sA + row * 64 + ((chunk ^ (li & 7)) << 3));
      }
      #pragma unroll
      for (int n = 0; n < 4; ++n) {
        const int row = wc * 64 + n * 16 + li;
        bfr[n] = *(const s16x8*)(sB + row * 64 + ((chunk ^ (li & 7)) << 3));
      }
      #pragma unroll
      for (int m = 0; m < 4; ++m)
        #pragma unroll
        for (int n = 0; n < 4; ++n)
          acc[m][n] = __builtin_amdgcn_mfma_f32_16x16x32_bf16(af[m], bfr[n], acc[m][n], 0, 0, 0);
    }
    __syncthreads();
  }
}

// ---------------- fused QKV projection + RoPE (+ V transpose) ----------------
// grid: x = 24 col-blocks (16 Q | 4 K | 4 V), y = 16 row-blocks
__global__ __launch_bounds__(256) void qkv_kernel(
    const short* __restrict__ h16, const short* __restrict__ wq,
    const short* __restrict__ wk, const short* __restrict__ wv,
    short* __restrict__ qo, short* __restrict__ ko, short* __restrict__ vto,
    const float* __restrict__ rc, const float* __restrict__ rs) {
  __shared__ short sA[128 * 64];
  __shared__ short sB[128 * 64];
  const int cb = blockIdx.x, rb = blockIdx.y;
  const short* B; short* out; int colbase, mode; int64_t ldc;
  if (cb < 16)      { B = wq + (int64_t)cb * 128 * HID;        out = qo;  colbase = cb * 128;        mode = 0; ldc = HID;   }
  else if (cb < 20) { B = wk + (int64_t)(cb - 16) * 128 * HID; out = ko;  colbase = (cb - 16) * 128; mode = 0; ldc = KVDIM; }
  else              { B = wv + (int64_t)(cb - 20) * 128 * HID; out = vto; colbase = (cb - 20) * 128; mode = 1; ldc = L_SEQ; }

  f32x4 acc[4][4];
  const f32x4 z = {0.f, 0.f, 0.f, 0.f};
  #pragma unroll
  for (int m = 0; m < 4; ++m)
    #pragma unroll
    for (int n = 0; n < 4; ++n) acc[m][n] = z;

  gemm_core_128(h16 + (int64_t)rb * 128 * HID, B, sA, sB, acc);

  const int lane = threadIdx.x & 63;
  const int w = threadIdx.x >> 6, wr = w >> 1, wc = w & 1;
  const int g = lane >> 4, li = lane & 15;

  if (mode == 0) {
    // RoPE fused: pair partner (col^1) is the adjacent lane.
    #pragma unroll
    for (int m = 0; m < 4; ++m) {
      #pragma unroll
      for (int n = 0; n < 4; ++n) {
        const int col = colbase + wc * 64 + n * 16 + li;
        const int d2 = col & 62;           // table index: (d & ~1) within head
        #pragma unroll
        for (int r = 0; r < 4; ++r) {
          const int row = rb * 128 + wr * 64 + m * 16 + g * 4 + r;
          const float c = rc[row * 64 + d2];
          const float s = rs[row * 64 + d2];
          const float v0 = acc[m][n][r];
          const float pr = __shfl_xor(v0, 1, 64);
          const float o = (lane & 1) ? (v0 * c + pr * s) : (v0 * c - pr * s);
          out[(int64_t)row * ldc + col] = f2bf(o);
        }
      }
    }
  } else {
    // V: store transposed as v_t[d_global][seq] so attention B-operand reads
    // are contiguous; pack the 4 row-regs into one 8B store.
    #pragma unroll
    for (int m = 0; m < 4; ++m) {
      #pragma unroll
      for (int n = 0; n < 4; ++n) {
        const int col = colbase + wc * 64 + n * 16 + li;        // 0..511
        const int row0 = rb * 128 + wr * 64 + m * 16 + g * 4;
        s16x4 pk;
        pk[0] = f2bf(acc[m][n][0]); pk[1] = f2bf(acc[m][n][1]);
        pk[2] = f2bf(acc[m][n][2]); pk[3] = f2bf(acc[m][n][3]);
        *(s16x4*)(out + (int64_t)col * L_SEQ + row0) = pk;
      }
    }
  }
}

// ---------------- causal GQA flash attention ----------------
// grid: x = L/64 q-blocks, y = NHEAD. 4 waves x 16 q-rows. Q in regs,
// K / V^T 64x64 tiles in swizzled LDS, online softmax, P via padded LDS.
__global__ __launch_bounds__(256) void attn_kernel(
    const short* __restrict__ q16, const short* __restrict__ k16,
    const short* __restrict__ vt16, short* __restrict__ out16) {
  __shared__ short sK[64 * 64];
  __shared__ short sV[64 * 64];           // V^T tile: [d][kv]
  __shared__ short sP[4][16 * 80];        // per-wave P, stride 80 (16B-aligned rows)
  const int qb = blockIdx.x, h = blockIdx.y, kvh = h >> 2;
  const int tid = threadIdx.x, lane = tid & 63, w = tid >> 6;
  const int g = lane >> 4, li = lane & 15;

  s16x8 qf[2];
  {
    const int qrow = qb * 64 + w * 16 + li;
    #pragma unroll
    for (int kk = 0; kk < 2; ++kk)
      qf[kk] = *(const s16x8*)(q16 + (int64_t)qrow * HID + h * 64 + kk * 32 + g * 8);
  }

  f32x4 accO[4];
  const f32x4 z = {0.f, 0.f, 0.f, 0.f};
  float mrow[4], lrow[4];
  #pragma unroll
  for (int n = 0; n < 4; ++n) accO[n] = z;
  #pragma unroll
  for (int r = 0; r < 4; ++r) { mrow[r] = -1e30f; lrow[r] = 0.f; }

  const int ntiles = qb + 1;
  for (int t = 0; t < ntiles; ++t) {
    const int kv0 = t * 64;
    // stage K tile and V^T tile
    #pragma unroll
    for (int i = 0; i < 2; ++i) {
      const int flat = i * 256 + tid;     // 0..511 chunks of 16B
      const int row = flat >> 3, c8 = flat & 7;
      const int slot = c8 ^ (row & 7);
      s16x8 kv = *(const s16x8*)(k16 + (int64_t)(kv0 + row) * KVDIM + kvh * 64 + c8 * 8);
      s16x8 vv = *(const s16x8*)(vt16 + (int64_t)(kvh * 64 + row) * L_SEQ + kv0 + c8 * 8);
      *(s16x8*)(sK + row * 64 + slot * 8) = kv;
      *(s16x8*)(sV + row * 64 + slot * 8) = vv;
    }
    __syncthreads();

    // S = Q K^T  (rows = q, cols = kv)
    f32x4 s[4];
    #pragma unroll
    for (int n = 0; n < 4; ++n) s[n] = z;
    #pragma unroll
    for (int kk = 0; kk < 2; ++kk) {
      const int chunk = (kk << 2) | g;
      #pragma unroll
      for (int n = 0; n < 4; ++n) {
        const int row = n * 16 + li;
        s16x8 kf = *(const s16x8*)(sK + row * 64 + ((chunk ^ (li & 7)) << 3));
        s[n] = __builtin_amdgcn_mfma_f32_16x16x32_bf16(qf[kk], kf, s[n], 0, 0, 0);
      }
    }

    // scale + causal mask (-1e30 -> exp underflows to 0; tile 0 always has
    // a valid diagonal element so mrow is real from the first tile)
    const int qr = qb * 64 + w * 16 + g * 4;
    #pragma unroll
    for (int n = 0; n < 4; ++n) {
      const int kvcol = kv0 + n * 16 + li;
      #pragma unroll
      for (int r = 0; r < 4; ++r)
        s[n][r] = (kvcol <= qr + r) ? s[n][r] * 0.125f : -1e30f;
    }

    // online softmax: row reduce across the 16 col-lanes
    float mx[4];
    #pragma unroll
    for (int r = 0; r < 4; ++r)
      mx[r] = fmaxf(fmaxf(s[0][r], s[1][r]), fmaxf(s[2][r], s[3][r]));
    #pragma unroll
    for (int off = 1; off < 16; off <<= 1)
      #pragma unroll
      for (int r = 0; r < 4; ++r) mx[r] = fmaxf(mx[r], __shfl_xor(mx[r], off, 64));
    float al[4];
    #pragma unroll
    for (int r = 0; r < 4; ++r) {
      const float mn = fmaxf(mrow[r], mx[r]);
      al[r] = __expf(mrow[r] - mn);
      mrow[r] = mn;
    }
    float ps[4] = {0.f, 0.f, 0.f, 0.f};
    #pragma unroll
    for (int n = 0; n < 4; ++n)
      #pragma unroll
      for (int r = 0; r < 4; ++r) {
        const float p = __expf(s[n][r] - mrow[r]);
        s[n][r] = p;
        ps[r] += p;
      }
    #pragma unroll
    for (int off = 1; off < 16; off <<= 1)
      #pragma unroll
      for (int r = 0; r < 4; ++r) ps[r] += __shfl_xor(ps[r], off, 64);
    #pragma unroll
    for (int r = 0; r < 4; ++r) lrow[r] = lrow[r] * al[r] + ps[r];
    #pragma unroll
    for (int n = 0; n < 4; ++n)
      #pragma unroll
      for (int r = 0; r < 4; ++r) accO[n][r] *= al[r];

    // P -> LDS (re-layout for PV A-operand)
    #pragma unroll
    for (int n = 0; n < 4; ++n)
      #pragma unroll
      for (int r = 0; r < 4; ++r)
        sP[w][(g * 4 + r) * 80 + n * 16 + li] = f2bf(s[n][r]);
    __syncthreads();

    // O += P V
    #pragma unroll
    for (int kk2 = 0; kk2 < 2; ++kk2) {
      s16x8 pf = *(const s16x8*)(&sP[w][li * 80 + kk2 * 32 + g * 8]);
      const int chunk = (kk2 << 2) | g;
      #pragma unroll
      for (int n2 = 0; n2 < 4; ++n2) {
        const int row = n2 * 16 + li;
        s16x8 vf = *(const s16x8*)(sV + row * 64 + ((chunk ^ (li & 7)) << 3));
        accO[n2] = __builtin_amdgcn_mfma_f32_16x16x32_bf16(pf, vf, accO[n2], 0, 0, 0);
      }
    }
    __syncthreads();
  }

  #pragma unroll
  for (int n2 = 0; n2 < 4; ++n2) {
    #pragma unroll
    for (int r = 0; r < 4; ++r) {
      const int row = qb * 64 + w * 16 + g * 4 + r;
      const int col = h * 64 + n2 * 16 + li;
      out16[(int64_t)row * HID + col] = f2bf(accO[n2][r] / lrow[r]);
    }
  }
}

// ---------------- O projection + residual ----------------
__global__ __launch_bounds__(256) void oproj_kernel(
    const short* __restrict__ ao, const short* __restrict__ wo,
    const float* __restrict__ resid, float* __restrict__ out) {
  __shared__ short sA[128 * 64];
  __shared__ short sB[128 * 64];
  const int cb = blockIdx.x, rb = blockIdx.y;
  f32x4 acc[4][4];
  const f32x4 z = {0.f, 0.f, 0.f, 0.f};
  #pragma unroll
  for (int m = 0; m < 4; ++m)
    #pragma unroll
    for (int n = 0; n < 4; ++n) acc[m][n] = z;

  gemm_core_128(ao + (int64_t)rb * 128 * HID, wo + (int64_t)cb * 128 * HID, sA, sB, acc);

  const int lane = threadIdx.x & 63;
  const int w = threadIdx.x >> 6, wr = w >> 1, wc = w & 1;
  const int g = lane >> 4, li = lane & 15;
  #pragma unroll
  for (int m = 0; m < 4; ++m) {
    #pragma unroll
    for (int n = 0; n < 4; ++n) {
      const int col = cb * 128 + wc * 64 + n * 16 + li;
      #pragma unroll
      for (int r = 0; r < 4; ++r) {
        const int row = rb * 128 + wr * 64 + m * 16 + g * 4 + r;
        out[(int64_t)row * HID + col] = acc[m][n][r] + resid[(int64_t)row * HID + col];
      }
    }
  }
}

extern "C" void kernel_launch(void* const* d_in, const int* in_sizes, int n_in,
                              void* d_out, int out_size, void* d_ws, size_t ws_size,
                              hipStream_t stream) {
  (void)in_sizes; (void)n_in; (void)out_size; (void)ws_size;
  const float* x      = (const float*)d_in[0];
  // d_in[1] = mask: unused, causal mask computed arithmetically
  const float* norm_w = (const float*)d_in[2];
  const float* Wq     = (const float*)d_in[3];
  const float* Wk     = (const float*)d_in[4];
  const float* Wv     = (const float*)d_in[5];
  const float* Wo     = (const float*)d_in[6];
  const float* rc     = (const float*)d_in[7];
  const float* rs     = (const float*)d_in[8];
  float* out = (float*)d_out;

  char* ws = (char*)d_ws;
  short* wq16 = (short*)(ws);                  // 8 MB
  short* wk16 = (short*)(ws + 8388608);        // 2 MB
  short* wv16 = (short*)(ws + 10485760);       // 2 MB
  short* wo16 = (short*)(ws + 12582912);       // 8 MB
  short* h16  = (short*)(ws + 20971520);       // 8 MB
  short* q16  = (short*)(ws + 29360128);       // 8 MB (post-RoPE)
  short* k16  = (short*)(ws + 37748736);       // 2 MB (post-RoPE)
  short* vt16 = (short*)(ws + 39845888);       // 2 MB ([512][2048] transposed)
  short* ao16 = (short*)(ws + 41943040);       // 8 MB
  // total 48 MB

  convert_weights_kernel<<<10240, 256, 0, stream>>>(Wq, Wk, Wv, Wo, wq16, wk16, wv16, wo16);
  rmsnorm_kernel<<<L_SEQ, 256, 0, stream>>>(x, norm_w, h16);
  qkv_kernel<<<dim3(24, 16), 256, 0, stream>>>(h16, wq16, wk16, wv16, q16, k16, vt16, rc, rs);
  attn_kernel<<<dim3(L_SEQ / 64, NHEAD), 256, 0, stream>>>(q16, k16, vt16, ao16);
  oproj_kernel<<<dim3(16, 16), 256, 0, stream>>>(ao16, wo16, x, out);
}

// Round 2
// 160.025 us; speedup vs baseline: 1.3959x; 1.3959x over previous
//
#include <hip/hip_runtime.h>
#include <stdint.h>

#define L_SEQ 2048
#define HID   2048
#define NHEAD 32
#define NKV   8
#define HD    64
#define KVDIM 512

typedef __attribute__((ext_vector_type(8))) short s16x8;
typedef __attribute__((ext_vector_type(4))) short s16x4;
typedef __attribute__((ext_vector_type(4))) float f32x4;

__device__ __forceinline__ short f2bf(float f) {
  union { float f; uint32_t u; } v; v.f = f;
  uint32_t r = v.u + 0x7fffu + ((v.u >> 16) & 1u);
  return (short)(r >> 16);
}

// async global->LDS, 16B per lane. LDS dest is wave-uniform base + lane*16,
// so dest must be linear in lane; swizzle is applied to the GLOBAL source
// (rule #21: linear dest + inverse-swz source + swz on read).
__device__ __forceinline__ void gload16(const void* g, void* l) {
  __builtin_amdgcn_global_load_lds(
      (const __attribute__((address_space(1))) void*)g,
      (__attribute__((address_space(3))) void*)l, 16, 0, 0);
}

// ---------------- weights f32 -> bf16 ----------------
__global__ __launch_bounds__(256) void convert_weights_kernel(
    const float* __restrict__ wq, const float* __restrict__ wk,
    const float* __restrict__ wv, const float* __restrict__ wo,
    short* __restrict__ owq, short* __restrict__ owk,
    short* __restrict__ owv, short* __restrict__ owo) {
  int64_t e = ((int64_t)blockIdx.x * 256 + threadIdx.x) * 4;
  const float* src; short* dst; int64_t o;
  if (e < 4194304)      { src = wq; dst = owq; o = e; }
  else if (e < 5242880) { src = wk; dst = owk; o = e - 4194304; }
  else if (e < 6291456) { src = wv; dst = owv; o = e - 5242880; }
  else                  { src = wo; dst = owo; o = e - 6291456; }
  f32x4 v = *(const f32x4*)(src + o);
  s16x4 b;
  b[0] = f2bf(v[0]); b[1] = f2bf(v[1]); b[2] = f2bf(v[2]); b[3] = f2bf(v[3]);
  *(s16x4*)(dst + o) = b;
}

// ---------------- RMSNorm (f32 in, bf16 out) ----------------
__global__ __launch_bounds__(256) void rmsnorm_kernel(
    const float* __restrict__ x, const float* __restrict__ w,
    short* __restrict__ h) {
  const int row = blockIdx.x, tid = threadIdx.x;
  const float* xr = x + (int64_t)row * HID + tid * 8;
  f32x4 a = *(const f32x4*)(xr);
  f32x4 b = *(const f32x4*)(xr + 4);
  float ss = a[0]*a[0]+a[1]*a[1]+a[2]*a[2]+a[3]*a[3]
           + b[0]*b[0]+b[1]*b[1]+b[2]*b[2]+b[3]*b[3];
  #pragma unroll
  for (int off = 1; off < 64; off <<= 1) ss += __shfl_xor(ss, off, 64);
  __shared__ float sred[4];
  if ((tid & 63) == 0) sred[tid >> 6] = ss;
  __syncthreads();
  const float scale = rsqrtf((sred[0]+sred[1]+sred[2]+sred[3]) * (1.0f/HID) + 1e-6f);
  const float* wp = w + tid * 8;
  f32x4 wa = *(const f32x4*)(wp);
  f32x4 wb = *(const f32x4*)(wp + 4);
  s16x8 o;
  o[0]=f2bf(a[0]*scale*wa[0]); o[1]=f2bf(a[1]*scale*wa[1]);
  o[2]=f2bf(a[2]*scale*wa[2]); o[3]=f2bf(a[3]*scale*wa[3]);
  o[4]=f2bf(b[0]*scale*wb[0]); o[5]=f2bf(b[1]*scale*wb[1]);
  o[6]=f2bf(b[2]*scale*wb[2]); o[7]=f2bf(b[3]*scale*wb[3]);
  *(s16x8*)(h + (int64_t)row * HID + tid * 8) = o;
}

// ---------------- GEMM core: C(128x128) = A(128xK) * B(128xK)^T, K=2048 ----
// global_load_lds staging: linear LDS dest, inverse-swizzled global source;
// reads use slot = chunk ^ (row&7) -> conflict-free ds_read_b128.
__device__ __forceinline__ void gemm_core_128(
    const short* __restrict__ A, const short* __restrict__ B,
    short* sA, short* sB, f32x4 acc[4][4]) {
  const int tid = threadIdx.x;
  const int lane = tid & 63;
  const int w = tid >> 6, wr = w >> 1, wc = w & 1;
  const int g = lane >> 4, li = lane & 15;
  for (int k0 = 0; k0 < HID; k0 += 64) {
    __syncthreads();                       // prev tile fully consumed
    #pragma unroll
    for (int i = 0; i < 4; ++i) {
      const int flat = i * 256 + tid;      // 0..1023 16B chunks
      const int row = flat >> 3, s = flat & 7;
      const int sc = s ^ (row & 7);        // inverse swizzle on source
      gload16(A + (int64_t)row * HID + k0 + sc * 8, sA + flat * 8);
      gload16(B + (int64_t)row * HID + k0 + sc * 8, sB + flat * 8);
    }
    __syncthreads();                       // loads landed
    #pragma unroll
    for (int kk = 0; kk < 2; ++kk) {
      s16x8 af[4], bfr[4];
      const int chunk = (kk << 2) | g;
      #pragma unroll
      for (int m = 0; m < 4; ++m) {
        const int row = wr * 64 + m * 16 + li;   // row&7 == li&7
        af[m] = *(const s16x8*)(sA + row * 64 + ((chunk ^ (li & 7)) << 3));
      }
      #pragma unroll
      for (int n = 0; n < 4; ++n) {
        const int row = wc * 64 + n * 16 + li;
        bfr[n] = *(const s16x8*)(sB + row * 64 + ((chunk ^ (li & 7)) << 3));
      }
      #pragma unroll
      for (int m = 0; m < 4; ++m)
        #pragma unroll
        for (int n = 0; n < 4; ++n)
          acc[m][n] = __builtin_amdgcn_mfma_f32_16x16x32_bf16(af[m], bfr[n], acc[m][n], 0, 0, 0);
    }
  }
}

// ---------------- fused QKV projection + RoPE (+ V transpose) ----------------
__global__ __launch_bounds__(256) void qkv_kernel(
    const short* __restrict__ h16, const short* __restrict__ wq,
    const short* __restrict__ wk, const short* __restrict__ wv,
    short* __restrict__ qo, short* __restrict__ ko, short* __restrict__ vto,
    const float* __restrict__ rc, const float* __restrict__ rs) {
  __shared__ short sA[128 * 64];
  __shared__ short sB[128 * 64];
  const int cb = blockIdx.x, rb = blockIdx.y;
  const short* B; short* out; int colbase, mode; int64_t ldc;
  if (cb < 16)      { B = wq + (int64_t)cb * 128 * HID;        out = qo;  colbase = cb * 128;        mode = 0; ldc = HID;   }
  else if (cb < 20) { B = wk + (int64_t)(cb - 16) * 128 * HID; out = ko;  colbase = (cb - 16) * 128; mode = 0; ldc = KVDIM; }
  else              { B = wv + (int64_t)(cb - 20) * 128 * HID; out = vto; colbase = (cb - 20) * 128; mode = 1; ldc = L_SEQ; }

  f32x4 acc[4][4];
  const f32x4 z = {0.f, 0.f, 0.f, 0.f};
  #pragma unroll
  for (int m = 0; m < 4; ++m)
    #pragma unroll
    for (int n = 0; n < 4; ++n) acc[m][n] = z;

  gemm_core_128(h16 + (int64_t)rb * 128 * HID, B, sA, sB, acc);

  const int lane = threadIdx.x & 63;
  const int w = threadIdx.x >> 6, wr = w >> 1, wc = w & 1;
  const int g = lane >> 4, li = lane & 15;

  if (mode == 0) {
    #pragma unroll
    for (int m = 0; m < 4; ++m) {
      #pragma unroll
      for (int n = 0; n < 4; ++n) {
        const int col = colbase + wc * 64 + n * 16 + li;
        const int d2 = col & 62;
        #pragma unroll
        for (int r = 0; r < 4; ++r) {
          const int row = rb * 128 + wr * 64 + m * 16 + g * 4 + r;
          const float c = rc[row * 64 + d2];
          const float s = rs[row * 64 + d2];
          const float v0 = acc[m][n][r];
          const float pr = __shfl_xor(v0, 1, 64);
          const float o = (lane & 1) ? (v0 * c + pr * s) : (v0 * c - pr * s);
          out[(int64_t)row * ldc + col] = f2bf(o);
        }
      }
    }
  } else {
    #pragma unroll
    for (int m = 0; m < 4; ++m) {
      #pragma unroll
      for (int n = 0; n < 4; ++n) {
        const int col = colbase + wc * 64 + n * 16 + li;
        const int row0 = rb * 128 + wr * 64 + m * 16 + g * 4;
        s16x4 pk;
        pk[0] = f2bf(acc[m][n][0]); pk[1] = f2bf(acc[m][n][1]);
        pk[2] = f2bf(acc[m][n][2]); pk[3] = f2bf(acc[m][n][3]);
        *(s16x4*)(out + (int64_t)col * L_SEQ + row0) = pk;
      }
    }
  }
}

// ---------------- causal GQA flash attention (swapped QK^T, paired q-blocks) --
// grid: x = 16 pairs (qbL=i, qbH=31-i), y = 32 heads. 4 waves x 16 q-rows per
// q-block. S^T = mfma(K,Q): lane owns ONE q-row -> scalar m/l, in-lane reduce
// + 2 shfl. P^T staged per-wave via 4 ds_write_b64, read back as b128 B-frags.
__device__ __forceinline__ void softmax_pv(
    f32x4 s[4], const s16x8 vf[2][4], bool diag,
    int w, int g, int li, short* sPw,
    float& m, float& l, f32x4 acc[4]) {
  if (diag) {
    const int ql = w * 16 + li;
    #pragma unroll
    for (int n = 0; n < 4; ++n)
      #pragma unroll
      for (int r = 0; r < 4; ++r) {
        const int kvl = n * 16 + g * 4 + r;
        s[n][r] = (kvl <= ql) ? s[n][r] * 0.125f : -1e30f;
      }
  } else {
    #pragma unroll
    for (int n = 0; n < 4; ++n)
      #pragma unroll
      for (int r = 0; r < 4; ++r) s[n][r] *= 0.125f;
  }
  float mx = s[0][0];
  #pragma unroll
  for (int n = 0; n < 4; ++n)
    #pragma unroll
    for (int r = 0; r < 4; ++r) mx = fmaxf(mx, s[n][r]);
  mx = fmaxf(mx, __shfl_xor(mx, 16, 64));
  mx = fmaxf(mx, __shfl_xor(mx, 32, 64));
  const float mn = fmaxf(m, mx);
  const float al = __expf(m - mn);
  m = mn;
  float ps = 0.f;
  #pragma unroll
  for (int n = 0; n < 4; ++n)
    #pragma unroll
    for (int r = 0; r < 4; ++r) {
      const float p = __expf(s[n][r] - mn);
      s[n][r] = p;
      ps += p;
    }
  ps += __shfl_xor(ps, 16, 64);
  ps += __shfl_xor(ps, 32, 64);
  l = l * al + ps;
  #pragma unroll
  for (int dt = 0; dt < 4; ++dt)
    #pragma unroll
    for (int r = 0; r < 4; ++r) acc[dt][r] *= al;
  // pack P^T rows (kv = n*16+g*4..+3, q = li) into swizzled [q][kv] buffer
  #pragma unroll
  for (int n = 0; n < 4; ++n) {
    s16x4 pk;
    #pragma unroll
    for (int r = 0; r < 4; ++r) pk[r] = f2bf(s[n][r]);
    *(s16x4*)(sPw + li * 64 + (((n * 2 + (g >> 1)) ^ (li & 7)) << 3) + (g & 1) * 4) = pk;
  }
  // PV: O^T[d][q] += V^T[d][kv] * P^T[kv][q]
  #pragma unroll
  for (int kk = 0; kk < 2; ++kk) {
    s16x8 pf = *(const s16x8*)(sPw + li * 64 + (((kk * 4 + g) ^ (li & 7)) << 3));
    #pragma unroll
    for (int dt = 0; dt < 4; ++dt)
      acc[dt] = __builtin_amdgcn_mfma_f32_16x16x32_bf16(vf[kk][dt], pf, acc[dt], 0, 0, 0);
  }
}

__device__ __forceinline__ void write_out(
    const f32x4 acc[4], float l, int qb, int h, int w, int g, int li, int lane,
    short* sPw, short* __restrict__ out16) {
  const float rl = 1.0f / l;
  #pragma unroll
  for (int n2 = 0; n2 < 4; ++n2) {
    s16x4 o;
    #pragma unroll
    for (int r = 0; r < 4; ++r) o[r] = f2bf(acc[n2][r] * rl);
    *(s16x4*)(sPw + li * 64 + (((n2 * 2 + (g >> 1)) ^ (li & 7)) << 3) + (g & 1) * 4) = o;
  }
  #pragma unroll
  for (int half = 0; half < 2; ++half) {
    const int chunk = half * 64 + lane;
    const int q = chunk >> 3, c = chunk & 7;
    s16x8 v = *(const s16x8*)(sPw + q * 64 + ((c ^ (q & 7)) << 3));
    *(s16x8*)(out16 + (int64_t)(qb * 64 + w * 16 + q) * HID + h * 64 + c * 8) = v;
  }
}

__global__ __launch_bounds__(256) void attn_kernel(
    const short* __restrict__ q16, const short* __restrict__ k16,
    const short* __restrict__ vt16, short* __restrict__ out16) {
  __shared__ short sK[64 * 64];
  __shared__ short sV[64 * 64];           // V^T tile: [d][kv]
  __shared__ short sP[4][16 * 64];        // per-wave P^T relayout / out transpose
  const int pi = blockIdx.x, h = blockIdx.y, kvh = h >> 2;
  const int qbL = pi, qbH = 31 - pi;
  const int tid = threadIdx.x, lane = tid & 63, w = tid >> 6;
  const int g = lane >> 4, li = lane & 15;
  short* sPw = &sP[w][0];

  s16x8 qfL[2], qfH[2];
  {
    const int qrL = qbL * 64 + w * 16 + li;
    const int qrH = qbH * 64 + w * 16 + li;
    #pragma unroll
    for (int kk = 0; kk < 2; ++kk) {
      qfL[kk] = *(const s16x8*)(q16 + (int64_t)qrL * HID + h * 64 + kk * 32 + g * 8);
      qfH[kk] = *(const s16x8*)(q16 + (int64_t)qrH * HID + h * 64 + kk * 32 + g * 8);
    }
  }

  f32x4 accL[4], accH[4];
  const f32x4 z = {0.f, 0.f, 0.f, 0.f};
  #pragma unroll
  for (int n = 0; n < 4; ++n) { accL[n] = z; accH[n] = z; }
  float mL = -1e30f, lL = 0.f, mH = -1e30f, lH = 0.f;

  for (int t = 0; t <= qbH; ++t) {
    const int kv0 = t * 64;
    __syncthreads();                       // prev tile fully consumed
    #pragma unroll
    for (int i = 0; i < 2; ++i) {
      const int flat = i * 256 + tid;      // 0..511 16B chunks
      const int row = flat >> 3, s = flat & 7;
      const int sc = s ^ (row & 7);
      gload16(k16 + (int64_t)(kv0 + row) * KVDIM + kvh * 64 + sc * 8, sK + flat * 8);
      gload16(vt16 + (int64_t)(kvh * 64 + row) * L_SEQ + kv0 + sc * 8, sV + flat * 8);
    }
    __syncthreads();                       // loads landed

    // shared K fragments (A-operand: row = kv)
    s16x8 kf[2][4];
    #pragma unroll
    for (int kk = 0; kk < 2; ++kk)
      #pragma unroll
      for (int n = 0; n < 4; ++n)
        kf[kk][n] = *(const s16x8*)(sK + (n * 16 + li) * 64 + ((((kk << 2) | g) ^ (li & 7)) << 3));

    const bool doLo = (t <= qbL);
    f32x4 sH[4], sL[4];
    #pragma unroll
    for (int n = 0; n < 4; ++n) sH[n] = z;
    #pragma unroll
    for (int kk = 0; kk < 2; ++kk)
      #pragma unroll
      for (int n = 0; n < 4; ++n)
        sH[n] = __builtin_amdgcn_mfma_f32_16x16x32_bf16(kf[kk][n], qfH[kk], sH[n], 0, 0, 0);
    if (doLo) {
      #pragma unroll
      for (int n = 0; n < 4; ++n) sL[n] = z;
      #pragma unroll
      for (int kk = 0; kk < 2; ++kk)
        #pragma unroll
        for (int n = 0; n < 4; ++n)
          sL[n] = __builtin_amdgcn_mfma_f32_16x16x32_bf16(kf[kk][n], qfL[kk], sL[n], 0, 0, 0);
    }

    // shared V^T fragments (A-operand: row = d)
    s16x8 vf[2][4];
    #pragma unroll
    for (int kk = 0; kk < 2; ++kk)
      #pragma unroll
      for (int dt = 0; dt < 4; ++dt)
        vf[kk][dt] = *(const s16x8*)(sV + (dt * 16 + li) * 64 + ((((kk << 2) | g) ^ (li & 7)) << 3));

    softmax_pv(sH, vf, t == qbH, w, g, li, sPw, mH, lH, accH);
    if (doLo) softmax_pv(sL, vf, t == qbL, w, g, li, sPw, mL, lL, accL);
  }

  write_out(accL, lL, qbL, h, w, g, li, lane, sPw, out16);
  write_out(accH, lH, qbH, h, w, g, li, lane, sPw, out16);
}

// ---------------- O projection + residual ----------------
__global__ __launch_bounds__(256) void oproj_kernel(
    const short* __restrict__ ao, const short* __restrict__ wo,
    const float* __restrict__ resid, float* __restrict__ out) {
  __shared__ short sA[128 * 64];
  __shared__ short sB[128 * 64];
  const int cb = blockIdx.x, rb = blockIdx.y;
  f32x4 acc[4][4];
  const f32x4 z = {0.f, 0.f, 0.f, 0.f};
  #pragma unroll
  for (int m = 0; m < 4; ++m)
    #pragma unroll
    for (int n = 0; n < 4; ++n) acc[m][n] = z;

  gemm_core_128(ao + (int64_t)rb * 128 * HID, wo + (int64_t)cb * 128 * HID, sA, sB, acc);

  const int lane = threadIdx.x & 63;
  const int w = threadIdx.x >> 6, wr = w >> 1, wc = w & 1;
  const int g = lane >> 4, li = lane & 15;
  #pragma unroll
  for (int m = 0; m < 4; ++m) {
    #pragma unroll
    for (int n = 0; n < 4; ++n) {
      const int col = cb * 128 + wc * 64 + n * 16 + li;
      #pragma unroll
      for (int r = 0; r < 4; ++r) {
        const int row = rb * 128 + wr * 64 + m * 16 + g * 4 + r;
        out[(int64_t)row * HID + col] = acc[m][n][r] + resid[(int64_t)row * HID + col];
      }
    }
  }
}

extern "C" void kernel_launch(void* const* d_in, const int* in_sizes, int n_in,
                              void* d_out, int out_size, void* d_ws, size_t ws_size,
                              hipStream_t stream) {
  (void)in_sizes; (void)n_in; (void)out_size; (void)ws_size;
  const float* x      = (const float*)d_in[0];
  const float* norm_w = (const float*)d_in[2];
  const float* Wq     = (const float*)d_in[3];
  const float* Wk     = (const float*)d_in[4];
  const float* Wv     = (const float*)d_in[5];
  const float* Wo     = (const float*)d_in[6];
  const float* rc     = (const float*)d_in[7];
  const float* rs     = (const float*)d_in[8];
  float* out = (float*)d_out;

  char* ws = (char*)d_ws;
  short* wq16 = (short*)(ws);
  short* wk16 = (short*)(ws + 8388608);
  short* wv16 = (short*)(ws + 10485760);
  short* wo16 = (short*)(ws + 12582912);
  short* h16  = (short*)(ws + 20971520);
  short* q16  = (short*)(ws + 29360128);
  short* k16  = (short*)(ws + 37748736);
  short* vt16 = (short*)(ws + 39845888);
  short* ao16 = (short*)(ws + 41943040);

  convert_weights_kernel<<<10240, 256, 0, stream>>>(Wq, Wk, Wv, Wo, wq16, wk16, wv16, wo16);
  rmsnorm_kernel<<<L_SEQ, 256, 0, stream>>>(x, norm_w, h16);
  qkv_kernel<<<dim3(24, 16), 256, 0, stream>>>(h16, wq16, wk16, wv16, q16, k16, vt16, rc, rs);
  attn_kernel<<<dim3(16, NHEAD), 256, 0, stream>>>(q16, k16, vt16, ao16);
  oproj_kernel<<<dim3(16, 16), 256, 0, stream>>>(ao16, wo16, x, out);
}

// Round 3
// 155.997 us; speedup vs baseline: 1.4319x; 1.0258x over previous
//
#include <hip/hip_runtime.h>
#include <stdint.h>

#define L_SEQ 2048
#define HID   2048
#define NHEAD 32
#define NKV   8
#define HD    64
#define KVDIM 512

typedef __attribute__((ext_vector_type(8))) short s16x8;
typedef __attribute__((ext_vector_type(4))) short s16x4;
typedef __attribute__((ext_vector_type(4))) float f32x4;

// native RNE f32->bf16 (v_cvt_pk_bf16_f32 on gfx950)
__device__ __forceinline__ short f2bf(float f) {
  __bf16 b = (__bf16)f;
  short s;
  __builtin_memcpy(&s, &b, 2);
  return s;
}

// async global->LDS, 16B/lane. Linear LDS dest + inverse-swizzled global
// source + swizzled read (rule #21).
__device__ __forceinline__ void gload16(const void* g, void* l) {
  __builtin_amdgcn_global_load_lds(
      (const __attribute__((address_space(1))) void*)g,
      (__attribute__((address_space(3))) void*)l, 16, 0, 0);
}

// ---------------- weights f32 -> bf16 ----------------
__global__ __launch_bounds__(256) void convert_weights_kernel(
    const float* __restrict__ wq, const float* __restrict__ wk,
    const float* __restrict__ wv, const float* __restrict__ wo,
    short* __restrict__ owq, short* __restrict__ owk,
    short* __restrict__ owv, short* __restrict__ owo) {
  int64_t e = ((int64_t)blockIdx.x * 256 + threadIdx.x) * 4;
  const float* src; short* dst; int64_t o;
  if (e < 4194304)      { src = wq; dst = owq; o = e; }
  else if (e < 5242880) { src = wk; dst = owk; o = e - 4194304; }
  else if (e < 6291456) { src = wv; dst = owv; o = e - 5242880; }
  else                  { src = wo; dst = owo; o = e - 6291456; }
  f32x4 v = *(const f32x4*)(src + o);
  s16x4 b;
  b[0] = f2bf(v[0]); b[1] = f2bf(v[1]); b[2] = f2bf(v[2]); b[3] = f2bf(v[3]);
  *(s16x4*)(dst + o) = b;
}

// ---------------- RMSNorm (f32 in, bf16 out) ----------------
__global__ __launch_bounds__(256) void rmsnorm_kernel(
    const float* __restrict__ x, const float* __restrict__ w,
    short* __restrict__ h) {
  const int row = blockIdx.x, tid = threadIdx.x;
  const float* xr = x + (int64_t)row * HID + tid * 8;
  f32x4 a = *(const f32x4*)(xr);
  f32x4 b = *(const f32x4*)(xr + 4);
  float ss = a[0]*a[0]+a[1]*a[1]+a[2]*a[2]+a[3]*a[3]
           + b[0]*b[0]+b[1]*b[1]+b[2]*b[2]+b[3]*b[3];
  #pragma unroll
  for (int off = 1; off < 64; off <<= 1) ss += __shfl_xor(ss, off, 64);
  __shared__ float sred[4];
  if ((tid & 63) == 0) sred[tid >> 6] = ss;
  __syncthreads();
  const float scale = rsqrtf((sred[0]+sred[1]+sred[2]+sred[3]) * (1.0f/HID) + 1e-6f);
  const float* wp = w + tid * 8;
  f32x4 wa = *(const f32x4*)(wp);
  f32x4 wb = *(const f32x4*)(wp + 4);
  s16x8 o;
  o[0]=f2bf(a[0]*scale*wa[0]); o[1]=f2bf(a[1]*scale*wa[1]);
  o[2]=f2bf(a[2]*scale*wa[2]); o[3]=f2bf(a[3]*scale*wa[3]);
  o[4]=f2bf(b[0]*scale*wb[0]); o[5]=f2bf(b[1]*scale*wb[1]);
  o[6]=f2bf(b[2]*scale*wb[2]); o[7]=f2bf(b[3]*scale*wb[3]);
  *(s16x8*)(h + (int64_t)row * HID + tid * 8) = o;
}

// ---------------- GEMM core: C(128x128) = A(128xK) * B(128xK)^T, K=2048 ----
// Double-buffered (T3 minimum 2-phase): issue next tile's global_load_lds
// right after the barrier, compute current tile under the in-flight loads.
// One barrier per K-step; its implicit vmcnt(0) drain lands the loads.
__device__ __forceinline__ void gemm_core_128(
    const short* __restrict__ A, const short* __restrict__ B,
    short* sA, short* sB, f32x4 acc[4][4]) {
  const int tid = threadIdx.x;
  const int lane = tid & 63;
  const int w = tid >> 6, wr = w >> 1, wc = w & 1;
  const int g = lane >> 4, li = lane & 15;

  auto stage = [&](int k0, int buf) {
    #pragma unroll
    for (int i = 0; i < 4; ++i) {
      const int flat = i * 256 + tid;      // 0..1023 16B chunks
      const int row = flat >> 3, c8 = flat & 7;
      const int sc = c8 ^ (row & 7);       // inverse swizzle on source
      gload16(A + (int64_t)row * HID + k0 + sc * 8, sA + buf * 8192 + flat * 8);
      gload16(B + (int64_t)row * HID + k0 + sc * 8, sB + buf * 8192 + flat * 8);
    }
  };

  stage(0, 0);
  for (int k0 = 0; k0 < HID; k0 += 64) {
    const int cur = (k0 >> 6) & 1;
    __syncthreads();                       // cur loads landed; prev buf free
    if (k0 + 64 < HID) stage(k0 + 64, cur ^ 1);
    const short* cA = sA + cur * 8192;
    const short* cB = sB + cur * 8192;
    #pragma unroll
    for (int kk = 0; kk < 2; ++kk) {
      s16x8 af[4], bfr[4];
      const int chunk = (kk << 2) | g;
      #pragma unroll
      for (int m = 0; m < 4; ++m) {
        const int row = wr * 64 + m * 16 + li;
        af[m] = *(const s16x8*)(cA + row * 64 + ((chunk ^ (li & 7)) << 3));
      }
      #pragma unroll
      for (int n = 0; n < 4; ++n) {
        const int row = wc * 64 + n * 16 + li;
        bfr[n] = *(const s16x8*)(cB + row * 64 + ((chunk ^ (li & 7)) << 3));
      }
      #pragma unroll
      for (int m = 0; m < 4; ++m)
        #pragma unroll
        for (int n = 0; n < 4; ++n)
          acc[m][n] = __builtin_amdgcn_mfma_f32_16x16x32_bf16(af[m], bfr[n], acc[m][n], 0, 0, 0);
    }
  }
}

// ---------------- fused QKV projection + RoPE (+ V transpose) ----------------
__global__ __launch_bounds__(256) void qkv_kernel(
    const short* __restrict__ h16, const short* __restrict__ wq,
    const short* __restrict__ wk, const short* __restrict__ wv,
    short* __restrict__ qo, short* __restrict__ ko, short* __restrict__ vto,
    const float* __restrict__ rc, const float* __restrict__ rs) {
  __shared__ short sA[2 * 128 * 64];
  __shared__ short sB[2 * 128 * 64];
  const int cb = blockIdx.x, rb = blockIdx.y;
  const short* B; short* out; int colbase, mode; int64_t ldc;
  if (cb < 16)      { B = wq + (int64_t)cb * 128 * HID;        out = qo;  colbase = cb * 128;        mode = 0; ldc = HID;   }
  else if (cb < 20) { B = wk + (int64_t)(cb - 16) * 128 * HID; out = ko;  colbase = (cb - 16) * 128; mode = 0; ldc = KVDIM; }
  else              { B = wv + (int64_t)(cb - 20) * 128 * HID; out = vto; colbase = (cb - 20) * 128; mode = 1; ldc = L_SEQ; }

  f32x4 acc[4][4];
  const f32x4 z = {0.f, 0.f, 0.f, 0.f};
  #pragma unroll
  for (int m = 0; m < 4; ++m)
    #pragma unroll
    for (int n = 0; n < 4; ++n) acc[m][n] = z;

  gemm_core_128(h16 + (int64_t)rb * 128 * HID, B, sA, sB, acc);

  const int lane = threadIdx.x & 63;
  const int w = threadIdx.x >> 6, wr = w >> 1, wc = w & 1;
  const int g = lane >> 4, li = lane & 15;

  if (mode == 0) {
    #pragma unroll
    for (int m = 0; m < 4; ++m) {
      #pragma unroll
      for (int n = 0; n < 4; ++n) {
        const int col = colbase + wc * 64 + n * 16 + li;
        const int d2 = col & 62;
        #pragma unroll
        for (int r = 0; r < 4; ++r) {
          const int row = rb * 128 + wr * 64 + m * 16 + g * 4 + r;
          const float c = rc[row * 64 + d2];
          const float s = rs[row * 64 + d2];
          const float v0 = acc[m][n][r];
          const float pr = __shfl_xor(v0, 1, 64);
          const float o = (lane & 1) ? (v0 * c + pr * s) : (v0 * c - pr * s);
          out[(int64_t)row * ldc + col] = f2bf(o);
        }
      }
    }
  } else {
    #pragma unroll
    for (int m = 0; m < 4; ++m) {
      #pragma unroll
      for (int n = 0; n < 4; ++n) {
        const int col = colbase + wc * 64 + n * 16 + li;
        const int row0 = rb * 128 + wr * 64 + m * 16 + g * 4;
        s16x4 pk;
        pk[0] = f2bf(acc[m][n][0]); pk[1] = f2bf(acc[m][n][1]);
        pk[2] = f2bf(acc[m][n][2]); pk[3] = f2bf(acc[m][n][3]);
        *(s16x4*)(out + (int64_t)col * L_SEQ + row0) = pk;
      }
    }
  }
}

// ---------------- causal GQA flash attention ----------------
// Swapped QK^T (lane owns one q-row -> scalar m/l), exp2-domain softmax with
// defer-max (T13), double-buffered K/V staging, setprio around MFMA (T5).
// grid: x = 32 q-blocks (descending size for LPT balance), y = 32 heads.
#define CSM 0.18033688f            /* log2(e)/8 */
#define DEFER_THR 44.3614f         /* 8 / CSM -> P bounded by 2^8 */

__global__ __launch_bounds__(256, 4) void attn_kernel(
    const short* __restrict__ q16, const short* __restrict__ k16,
    const short* __restrict__ vt16, short* __restrict__ out16) {
  __shared__ short sK[2 * 64 * 64];
  __shared__ short sV[2 * 64 * 64];       // V^T tile: [d][kv]
  __shared__ short sP[4][16 * 64];        // per-wave P^T relayout / out transpose
  const int qb = 31 - blockIdx.x;         // big blocks dispatch first
  const int h = blockIdx.y, kvh = h >> 2;
  const int tid = threadIdx.x, lane = tid & 63, w = tid >> 6;
  const int g = lane >> 4, li = lane & 15;
  short* sPw = &sP[w][0];

  s16x8 qf[2];
  {
    const int qr = qb * 64 + w * 16 + li;
    #pragma unroll
    for (int kk = 0; kk < 2; ++kk)
      qf[kk] = *(const s16x8*)(q16 + (int64_t)qr * HID + h * 64 + kk * 32 + g * 8);
  }

  f32x4 acc[4];
  const f32x4 z = {0.f, 0.f, 0.f, 0.f};
  #pragma unroll
  for (int n = 0; n < 4; ++n) acc[n] = z;
  float m = -1e30f, l = 0.f;

  auto stage = [&](int t, int buf) {
    const int kv0 = t * 64;
    #pragma unroll
    for (int i = 0; i < 2; ++i) {
      const int flat = i * 256 + tid;
      const int row = flat >> 3, c8 = flat & 7;
      const int sc = c8 ^ (row & 7);
      gload16(k16 + (int64_t)(kv0 + row) * KVDIM + kvh * 64 + sc * 8,
              sK + buf * 4096 + flat * 8);
      gload16(vt16 + (int64_t)(kvh * 64 + row) * L_SEQ + kv0 + sc * 8,
              sV + buf * 4096 + flat * 8);
    }
  };

  stage(0, 0);
  for (int t = 0; t <= qb; ++t) {
    const int cur = t & 1;
    __syncthreads();                       // cur tile landed; prev buf free
    if (t < qb) stage(t + 1, cur ^ 1);
    const short* cK = sK + cur * 4096;
    const short* cV = sV + cur * 4096;

    // S^T = K * Q
    s16x8 kf[2][4];
    #pragma unroll
    for (int kk = 0; kk < 2; ++kk)
      #pragma unroll
      for (int n = 0; n < 4; ++n)
        kf[kk][n] = *(const s16x8*)(cK + (n * 16 + li) * 64 + ((((kk << 2) | g) ^ (li & 7)) << 3));
    f32x4 s[4];
    #pragma unroll
    for (int n = 0; n < 4; ++n) s[n] = z;
    __builtin_amdgcn_s_setprio(1);
    #pragma unroll
    for (int kk = 0; kk < 2; ++kk)
      #pragma unroll
      for (int n = 0; n < 4; ++n)
        s[n] = __builtin_amdgcn_mfma_f32_16x16x32_bf16(kf[kk][n], qf[kk], s[n], 0, 0, 0);
    __builtin_amdgcn_s_setprio(0);

    // causal mask on diagonal tile
    if (t == qb) {
      const int ql = w * 16 + li;
      #pragma unroll
      for (int n = 0; n < 4; ++n)
        #pragma unroll
        for (int r = 0; r < 4; ++r) {
          const int kvl = n * 16 + g * 4 + r;
          if (kvl > ql) s[n][r] = -1e30f;
        }
    }

    // online softmax (exp2 domain, raw-S max tracking, defer-max)
    float mx = fmaxf(fmaxf(s[0][0], s[0][1]), fmaxf(s[0][2], s[0][3]));
    #pragma unroll
    for (int n = 1; n < 4; ++n)
      mx = fmaxf(mx, fmaxf(fmaxf(s[n][0], s[n][1]), fmaxf(s[n][2], s[n][3])));
    mx = fmaxf(mx, __shfl_xor(mx, 16, 64));
    mx = fmaxf(mx, __shfl_xor(mx, 32, 64));
    if (mx > m + DEFER_THR) {              // rare after first tile
      const float al = __builtin_amdgcn_exp2f((m - mx) * CSM);
      m = mx;
      l *= al;
      #pragma unroll
      for (int dt = 0; dt < 4; ++dt)
        #pragma unroll
        for (int r = 0; r < 4; ++r) acc[dt][r] *= al;
    }
    const float nmc = -m * CSM;
    float ps = 0.f;
    #pragma unroll
    for (int n = 0; n < 4; ++n)
      #pragma unroll
      for (int r = 0; r < 4; ++r) {
        const float p = __builtin_amdgcn_exp2f(fmaf(s[n][r], CSM, nmc));
        s[n][r] = p;
        ps += p;
      }
    ps += __shfl_xor(ps, 16, 64);
    ps += __shfl_xor(ps, 32, 64);
    l += ps;

    // pack P^T (kv = n*16+g*4..+3, q = li) into swizzled per-wave [q][kv]
    #pragma unroll
    for (int n = 0; n < 4; ++n) {
      s16x4 pk;
      #pragma unroll
      for (int r = 0; r < 4; ++r) pk[r] = f2bf(s[n][r]);
      *(s16x4*)(sPw + li * 64 + (((n * 2 + (g >> 1)) ^ (li & 7)) << 3) + (g & 1) * 4) = pk;
    }

    // O^T[d][q] += V^T[d][kv] * P^T[kv][q]
    s16x8 vf[2][4];
    #pragma unroll
    for (int kk = 0; kk < 2; ++kk)
      #pragma unroll
      for (int dt = 0; dt < 4; ++dt)
        vf[kk][dt] = *(const s16x8*)(cV + (dt * 16 + li) * 64 + ((((kk << 2) | g) ^ (li & 7)) << 3));
    #pragma unroll
    for (int kk = 0; kk < 2; ++kk) {
      s16x8 pf = *(const s16x8*)(sPw + li * 64 + (((kk * 4 + g) ^ (li & 7)) << 3));
      __builtin_amdgcn_s_setprio(1);
      #pragma unroll
      for (int dt = 0; dt < 4; ++dt)
        acc[dt] = __builtin_amdgcn_mfma_f32_16x16x32_bf16(vf[kk][dt], pf, acc[dt], 0, 0, 0);
      __builtin_amdgcn_s_setprio(0);
    }
  }

  // normalize, transpose via sPw, coalesced 16B stores
  const float rl = 1.0f / l;
  #pragma unroll
  for (int n2 = 0; n2 < 4; ++n2) {
    s16x4 o;
    #pragma unroll
    for (int r = 0; r < 4; ++r) o[r] = f2bf(acc[n2][r] * rl);
    *(s16x4*)(sPw + li * 64 + (((n2 * 2 + (g >> 1)) ^ (li & 7)) << 3) + (g & 1) * 4) = o;
  }
  #pragma unroll
  for (int half = 0; half < 2; ++half) {
    const int chunk = half * 64 + lane;
    const int q = chunk >> 3, c = chunk & 7;
    s16x8 v = *(const s16x8*)(sPw + q * 64 + ((c ^ (q & 7)) << 3));
    *(s16x8*)(out16 + (int64_t)(qb * 64 + w * 16 + q) * HID + h * 64 + c * 8) = v;
  }
}

// ---------------- O projection + residual ----------------
__global__ __launch_bounds__(256) void oproj_kernel(
    const short* __restrict__ ao, const short* __restrict__ wo,
    const float* __restrict__ resid, float* __restrict__ out) {
  __shared__ short sA[2 * 128 * 64];
  __shared__ short sB[2 * 128 * 64];
  const int cb = blockIdx.x, rb = blockIdx.y;
  f32x4 acc[4][4];
  const f32x4 z = {0.f, 0.f, 0.f, 0.f};
  #pragma unroll
  for (int m = 0; m < 4; ++m)
    #pragma unroll
    for (int n = 0; n < 4; ++n) acc[m][n] = z;

  gemm_core_128(ao + (int64_t)rb * 128 * HID, wo + (int64_t)cb * 128 * HID, sA, sB, acc);

  const int lane = threadIdx.x & 63;
  const int w = threadIdx.x >> 6, wr = w >> 1, wc = w & 1;
  const int g = lane >> 4, li = lane & 15;
  #pragma unroll
  for (int m = 0; m < 4; ++m) {
    #pragma unroll
    for (int n = 0; n < 4; ++n) {
      const int col = cb * 128 + wc * 64 + n * 16 + li;
      #pragma unroll
      for (int r = 0; r < 4; ++r) {
        const int row = rb * 128 + wr * 64 + m * 16 + g * 4 + r;
        out[(int64_t)row * HID + col] = acc[m][n][r] + resid[(int64_t)row * HID + col];
      }
    }
  }
}

extern "C" void kernel_launch(void* const* d_in, const int* in_sizes, int n_in,
                              void* d_out, int out_size, void* d_ws, size_t ws_size,
                              hipStream_t stream) {
  (void)in_sizes; (void)n_in; (void)out_size; (void)ws_size;
  const float* x      = (const float*)d_in[0];
  const float* norm_w = (const float*)d_in[2];
  const float* Wq     = (const float*)d_in[3];
  const float* Wk     = (const float*)d_in[4];
  const float* Wv     = (const float*)d_in[5];
  const float* Wo     = (const float*)d_in[6];
  const float* rc     = (const float*)d_in[7];
  const float* rs     = (const float*)d_in[8];
  float* out = (float*)d_out;

  char* ws = (char*)d_ws;
  short* wq16 = (short*)(ws);
  short* wk16 = (short*)(ws + 8388608);
  short* wv16 = (short*)(ws + 10485760);
  short* wo16 = (short*)(ws + 12582912);
  short* h16  = (short*)(ws + 20971520);
  short* q16  = (short*)(ws + 29360128);
  short* k16  = (short*)(ws + 37748736);
  short* vt16 = (short*)(ws + 39845888);
  short* ao16 = (short*)(ws + 41943040);

  convert_weights_kernel<<<10240, 256, 0, stream>>>(Wq, Wk, Wv, Wo, wq16, wk16, wv16, wo16);
  rmsnorm_kernel<<<L_SEQ, 256, 0, stream>>>(x, norm_w, h16);
  qkv_kernel<<<dim3(24, 16), 256, 0, stream>>>(h16, wq16, wk16, wv16, q16, k16, vt16, rc, rs);
  attn_kernel<<<dim3(32, NHEAD), 256, 0, stream>>>(q16, k16, vt16, ao16);
  oproj_kernel<<<dim3(16, 16), 256, 0, stream>>>(ao16, wo16, x, out);
}

// Round 8
// 143.544 us; speedup vs baseline: 1.5561x; 1.0868x over previous
//
#include <hip/hip_runtime.h>
#include <stdint.h>

#define L_SEQ 2048
#define HID   2048
#define NHEAD 32
#define NKV   8
#define HD    64
#define KVDIM 512

typedef __attribute__((ext_vector_type(8))) short s16x8;
typedef __attribute__((ext_vector_type(4))) short s16x4;
typedef __attribute__((ext_vector_type(4))) float f32x4;

// native RNE f32->bf16 (v_cvt_pk_bf16_f32 on gfx950)
__device__ __forceinline__ short f2bf(float f) {
  __bf16 b = (__bf16)f;
  short s;
  __builtin_memcpy(&s, &b, 2);
  return s;
}

// async global->LDS, 16B/lane. Linear LDS dest + inverse-swizzled global
// source + swizzled read (rule #21).
__device__ __forceinline__ void gload16(const void* g, void* l) {
  __builtin_amdgcn_global_load_lds(
      (const __attribute__((address_space(1))) void*)g,
      (__attribute__((address_space(3))) void*)l, 16, 0, 0);
}

// ---------------- weights f32 -> bf16 ----------------
__global__ __launch_bounds__(256) void convert_weights_kernel(
    const float* __restrict__ wq, const float* __restrict__ wk,
    const float* __restrict__ wv, const float* __restrict__ wo,
    short* __restrict__ owq, short* __restrict__ owk,
    short* __restrict__ owv, short* __restrict__ owo) {
  int64_t e = ((int64_t)blockIdx.x * 256 + threadIdx.x) * 4;
  const float* src; short* dst; int64_t o;
  if (e < 4194304)      { src = wq; dst = owq; o = e; }
  else if (e < 5242880) { src = wk; dst = owk; o = e - 4194304; }
  else if (e < 6291456) { src = wv; dst = owv; o = e - 5242880; }
  else                  { src = wo; dst = owo; o = e - 6291456; }
  f32x4 v = *(const f32x4*)(src + o);
  s16x4 b;
  b[0] = f2bf(v[0]); b[1] = f2bf(v[1]); b[2] = f2bf(v[2]); b[3] = f2bf(v[3]);
  *(s16x4*)(dst + o) = b;
}

// ---------------- RMSNorm (f32 in, bf16 out) ----------------
__global__ __launch_bounds__(256) void rmsnorm_kernel(
    const float* __restrict__ x, const float* __restrict__ w,
    short* __restrict__ h) {
  const int row = blockIdx.x, tid = threadIdx.x;
  const float* xr = x + (int64_t)row * HID + tid * 8;
  f32x4 a = *(const f32x4*)(xr);
  f32x4 b = *(const f32x4*)(xr + 4);
  float ss = a[0]*a[0]+a[1]*a[1]+a[2]*a[2]+a[3]*a[3]
           + b[0]*b[0]+b[1]*b[1]+b[2]*b[2]+b[3]*b[3];
  #pragma unroll
  for (int off = 1; off < 64; off <<= 1) ss += __shfl_xor(ss, off, 64);
  __shared__ float sred[4];
  if ((tid & 63) == 0) sred[tid >> 6] = ss;
  __syncthreads();
  const float scale = rsqrtf((sred[0]+sred[1]+sred[2]+sred[3]) * (1.0f/HID) + 1e-6f);
  const float* wp = w + tid * 8;
  f32x4 wa = *(const f32x4*)(wp);
  f32x4 wb = *(const f32x4*)(wp + 4);
  s16x8 o;
  o[0]=f2bf(a[0]*scale*wa[0]); o[1]=f2bf(a[1]*scale*wa[1]);
  o[2]=f2bf(a[2]*scale*wa[2]); o[3]=f2bf(a[3]*scale*wa[3]);
  o[4]=f2bf(b[0]*scale*wb[0]); o[5]=f2bf(b[1]*scale*wb[1]);
  o[6]=f2bf(b[2]*scale*wb[2]); o[7]=f2bf(b[3]*scale*wb[3]);
  *(s16x8*)(h + (int64_t)row * HID + tid * 8) = o;
}

// ---------------- GEMM core: C(128x128) = A(128xK) * B(128xK)^T, K=2048 ----
// Double-buffered 2-phase: issue next tile's global_load_lds right after the
// barrier, compute current tile under the in-flight loads.
__device__ __forceinline__ void gemm_core_128(
    const short* __restrict__ A, const short* __restrict__ B,
    short* sA, short* sB, f32x4 acc[4][4]) {
  const int tid = threadIdx.x;
  const int lane = tid & 63;
  const int w = tid >> 6, wr = w >> 1, wc = w & 1;
  const int g = lane >> 4, li = lane & 15;

  auto stage = [&](int k0, int buf) {
    #pragma unroll
    for (int i = 0; i < 4; ++i) {
      const int flat = i * 256 + tid;      // 0..1023 16B chunks
      const int row = flat >> 3, c8 = flat & 7;
      const int sc = c8 ^ (row & 7);       // inverse swizzle on source
      gload16(A + (int64_t)row * HID + k0 + sc * 8, sA + buf * 8192 + flat * 8);
      gload16(B + (int64_t)row * HID + k0 + sc * 8, sB + buf * 8192 + flat * 8);
    }
  };

  stage(0, 0);
  for (int k0 = 0; k0 < HID; k0 += 64) {
    const int cur = (k0 >> 6) & 1;
    __syncthreads();                       // cur loads landed; prev buf free
    if (k0 + 64 < HID) stage(k0 + 64, cur ^ 1);
    const short* cA = sA + cur * 8192;
    const short* cB = sB + cur * 8192;
    #pragma unroll
    for (int kk = 0; kk < 2; ++kk) {
      s16x8 af[4], bfr[4];
      const int chunk = (kk << 2) | g;
      #pragma unroll
      for (int m = 0; m < 4; ++m) {
        const int row = wr * 64 + m * 16 + li;
        af[m] = *(const s16x8*)(cA + row * 64 + ((chunk ^ (li & 7)) << 3));
      }
      #pragma unroll
      for (int n = 0; n < 4; ++n) {
        const int row = wc * 64 + n * 16 + li;
        bfr[n] = *(const s16x8*)(cB + row * 64 + ((chunk ^ (li & 7)) << 3));
      }
      #pragma unroll
      for (int m = 0; m < 4; ++m)
        #pragma unroll
        for (int n = 0; n < 4; ++n)
          acc[m][n] = __builtin_amdgcn_mfma_f32_16x16x32_bf16(af[m], bfr[n], acc[m][n], 0, 0, 0);
    }
  }
}

// ---------------- fused QKV projection + RoPE (+ V transpose) ----------------
__global__ __launch_bounds__(256) void qkv_kernel(
    const short* __restrict__ h16, const short* __restrict__ wq,
    const short* __restrict__ wk, const short* __restrict__ wv,
    short* __restrict__ qo, short* __restrict__ ko, short* __restrict__ vto,
    const float* __restrict__ rc, const float* __restrict__ rs) {
  __shared__ short sA[2 * 128 * 64];
  __shared__ short sB[2 * 128 * 64];
  const int cb = blockIdx.x, rb = blockIdx.y;
  const short* B; short* out; int colbase, mode; int64_t ldc;
  if (cb < 16)      { B = wq + (int64_t)cb * 128 * HID;        out = qo;  colbase = cb * 128;        mode = 0; ldc = HID;   }
  else if (cb < 20) { B = wk + (int64_t)(cb - 16) * 128 * HID; out = ko;  colbase = (cb - 16) * 128; mode = 0; ldc = KVDIM; }
  else              { B = wv + (int64_t)(cb - 20) * 128 * HID; out = vto; colbase = (cb - 20) * 128; mode = 1; ldc = L_SEQ; }

  f32x4 acc[4][4];
  const f32x4 z = {0.f, 0.f, 0.f, 0.f};
  #pragma unroll
  for (int m = 0; m < 4; ++m)
    #pragma unroll
    for (int n = 0; n < 4; ++n) acc[m][n] = z;

  gemm_core_128(h16 + (int64_t)rb * 128 * HID, B, sA, sB, acc);

  const int lane = threadIdx.x & 63;
  const int w = threadIdx.x >> 6, wr = w >> 1, wc = w & 1;
  const int g = lane >> 4, li = lane & 15;

  if (mode == 0) {
    #pragma unroll
    for (int m = 0; m < 4; ++m) {
      #pragma unroll
      for (int n = 0; n < 4; ++n) {
        const int col = colbase + wc * 64 + n * 16 + li;
        const int d2 = col & 62;
        #pragma unroll
        for (int r = 0; r < 4; ++r) {
          const int row = rb * 128 + wr * 64 + m * 16 + g * 4 + r;
          const float c = rc[row * 64 + d2];
          const float s = rs[row * 64 + d2];
          const float v0 = acc[m][n][r];
          const float pr = __shfl_xor(v0, 1, 64);
          const float o = (lane & 1) ? (v0 * c + pr * s) : (v0 * c - pr * s);
          out[(int64_t)row * ldc + col] = f2bf(o);
        }
      }
    }
  } else {
    #pragma unroll
    for (int m = 0; m < 4; ++m) {
      #pragma unroll
      for (int n = 0; n < 4; ++n) {
        const int col = colbase + wc * 64 + n * 16 + li;
        const int row0 = rb * 128 + wr * 64 + m * 16 + g * 4;
        s16x4 pk;
        pk[0] = f2bf(acc[m][n][0]); pk[1] = f2bf(acc[m][n][1]);
        pk[2] = f2bf(acc[m][n][2]); pk[3] = f2bf(acc[m][n][3]);
        *(s16x4*)(out + (int64_t)col * L_SEQ + row0) = pk;
      }
    }
  }
}

// ---------------- causal GQA flash attention (R2 structure + R3 safe opts) --
// Paired q-blocks (qbL=i, qbH=31-i -> uniform 33 tiles/block), swapped QK^T
// (lane owns one q-row -> scalar m/l), K/V frags shared across the pair,
// double-buffered staging (one barrier/tile), exp2-domain softmax with
// defer-max (T13), setprio around MFMA (T5). Fully deterministic.
#define CSM 0.18033688f            /* log2(e)/8 */
#define DEFER_THR 44.3614f         /* 8 / CSM -> P bounded by 2^8 */

__device__ __forceinline__ void softmax_pv(
    f32x4 s[4], const s16x8 vf[2][4], bool diag,
    int w, int g, int li, short* sPw,
    float& m, float& l, f32x4 acc[4]) {
  if (diag) {
    const int ql = w * 16 + li;
    #pragma unroll
    for (int n = 0; n < 4; ++n)
      #pragma unroll
      for (int r = 0; r < 4; ++r)
        if (n * 16 + g * 4 + r > ql) s[n][r] = -1e30f;
  }
  float mx = fmaxf(fmaxf(s[0][0], s[0][1]), fmaxf(s[0][2], s[0][3]));
  #pragma unroll
  for (int n = 1; n < 4; ++n)
    mx = fmaxf(mx, fmaxf(fmaxf(s[n][0], s[n][1]), fmaxf(s[n][2], s[n][3])));
  mx = fmaxf(mx, __shfl_xor(mx, 16, 64));
  mx = fmaxf(mx, __shfl_xor(mx, 32, 64));
  if (__any(mx > m + DEFER_THR)) {         // rare after early tiles
    const float mn = fmaxf(m, mx);
    const float al = __builtin_amdgcn_exp2f((m - mn) * CSM);
    m = mn;
    l *= al;
    #pragma unroll
    for (int dt = 0; dt < 4; ++dt)
      #pragma unroll
      for (int r = 0; r < 4; ++r) acc[dt][r] *= al;
  }
  const float nmc = -m * CSM;
  float ps = 0.f;
  #pragma unroll
  for (int n = 0; n < 4; ++n) {
    s16x4 pk;
    #pragma unroll
    for (int r = 0; r < 4; ++r) {
      const float p = __builtin_amdgcn_exp2f(fmaf(s[n][r], CSM, nmc));
      pk[r] = f2bf(p);
      ps += p;
    }
    *(s16x4*)(sPw + li * 64 + (((n * 2 + (g >> 1)) ^ (li & 7)) << 3) + (g & 1) * 4) = pk;
  }
  ps += __shfl_xor(ps, 16, 64);
  ps += __shfl_xor(ps, 32, 64);
  l += ps;
  // PV: O^T[d][q] += V^T[d][kv] * P^T[kv][q]
  #pragma unroll
  for (int kk = 0; kk < 2; ++kk) {
    s16x8 pf = *(const s16x8*)(sPw + li * 64 + (((kk * 4 + g) ^ (li & 7)) << 3));
    __builtin_amdgcn_s_setprio(1);
    #pragma unroll
    for (int dt = 0; dt < 4; ++dt)
      acc[dt] = __builtin_amdgcn_mfma_f32_16x16x32_bf16(vf[kk][dt], pf, acc[dt], 0, 0, 0);
    __builtin_amdgcn_s_setprio(0);
  }
}

__device__ __forceinline__ void write_out(
    const f32x4 acc[4], float l, int qb, int h, int w, int g, int li, int lane,
    short* sPw, short* __restrict__ out16) {
  const float rl = 1.0f / l;
  #pragma unroll
  for (int n2 = 0; n2 < 4; ++n2) {
    s16x4 o;
    #pragma unroll
    for (int r = 0; r < 4; ++r) o[r] = f2bf(acc[n2][r] * rl);
    *(s16x4*)(sPw + li * 64 + (((n2 * 2 + (g >> 1)) ^ (li & 7)) << 3) + (g & 1) * 4) = o;
  }
  #pragma unroll
  for (int half = 0; half < 2; ++half) {
    const int chunk = half * 64 + lane;
    const int q = chunk >> 3, c = chunk & 7;
    s16x8 v = *(const s16x8*)(sPw + q * 64 + ((c ^ (q & 7)) << 3));
    *(s16x8*)(out16 + (int64_t)(qb * 64 + w * 16 + q) * HID + h * 64 + c * 8) = v;
  }
}

__global__ __launch_bounds__(256) void attn_kernel(
    const short* __restrict__ q16, const short* __restrict__ k16,
    const short* __restrict__ vt16, short* __restrict__ out16) {
  __shared__ short sK[2 * 64 * 64];
  __shared__ short sV[2 * 64 * 64];       // V^T tile: [d][kv]
  __shared__ short sP[4][16 * 64];        // per-wave P^T relayout / out transpose
  const int pi = blockIdx.x, h = blockIdx.y, kvh = h >> 2;
  const int qbL = pi, qbH = 31 - pi;
  const int tid = threadIdx.x, lane = tid & 63, w = tid >> 6;
  const int g = lane >> 4, li = lane & 15;
  short* sPw = &sP[w][0];

  s16x8 qfL[2], qfH[2];
  {
    const int qrL = qbL * 64 + w * 16 + li;
    const int qrH = qbH * 64 + w * 16 + li;
    #pragma unroll
    for (int kk = 0; kk < 2; ++kk) {
      qfL[kk] = *(const s16x8*)(q16 + (int64_t)qrL * HID + h * 64 + kk * 32 + g * 8);
      qfH[kk] = *(const s16x8*)(q16 + (int64_t)qrH * HID + h * 64 + kk * 32 + g * 8);
    }
  }

  f32x4 accL[4], accH[4];
  const f32x4 z = {0.f, 0.f, 0.f, 0.f};
  #pragma unroll
  for (int n = 0; n < 4; ++n) { accL[n] = z; accH[n] = z; }
  float mL = -1e30f, lL = 0.f, mH = -1e30f, lH = 0.f;

  auto stage = [&](int t, int buf) {
    const int kv0 = t * 64;
    #pragma unroll
    for (int i = 0; i < 2; ++i) {
      const int flat = i * 256 + tid;      // 0..511 16B chunks
      const int row = flat >> 3, c8 = flat & 7;
      const int sc = c8 ^ (row & 7);
      gload16(k16 + (int64_t)(kv0 + row) * KVDIM + kvh * 64 + sc * 8,
              sK + buf * 4096 + flat * 8);
      gload16(vt16 + (int64_t)(kvh * 64 + row) * L_SEQ + kv0 + sc * 8,
              sV + buf * 4096 + flat * 8);
    }
  };

  stage(0, 0);
  for (int t = 0; t <= qbH; ++t) {
    const int cur = t & 1;
    __syncthreads();                       // cur tile landed; prev buf free
    if (t < qbH) stage(t + 1, cur ^ 1);
    const short* cK = sK + cur * 4096;
    const short* cV = sV + cur * 4096;

    // shared K fragments (A-operand: row = kv)
    s16x8 kf[2][4];
    #pragma unroll
    for (int kk = 0; kk < 2; ++kk)
      #pragma unroll
      for (int n = 0; n < 4; ++n)
        kf[kk][n] = *(const s16x8*)(cK + (n * 16 + li) * 64 + ((((kk << 2) | g) ^ (li & 7)) << 3));

    const bool doLo = (t <= qbL);
    f32x4 sH[4], sL[4];
    #pragma unroll
    for (int n = 0; n < 4; ++n) sH[n] = z;
    __builtin_amdgcn_s_setprio(1);
    #pragma unroll
    for (int kk = 0; kk < 2; ++kk)
      #pragma unroll
      for (int n = 0; n < 4; ++n)
        sH[n] = __builtin_amdgcn_mfma_f32_16x16x32_bf16(kf[kk][n], qfH[kk], sH[n], 0, 0, 0);
    __builtin_amdgcn_s_setprio(0);
    if (doLo) {
      #pragma unroll
      for (int n = 0; n < 4; ++n) sL[n] = z;
      __builtin_amdgcn_s_setprio(1);
      #pragma unroll
      for (int kk = 0; kk < 2; ++kk)
        #pragma unroll
        for (int n = 0; n < 4; ++n)
          sL[n] = __builtin_amdgcn_mfma_f32_16x16x32_bf16(kf[kk][n], qfL[kk], sL[n], 0, 0, 0);
      __builtin_amdgcn_s_setprio(0);
    }

    // shared V^T fragments (A-operand: row = d)
    s16x8 vf[2][4];
    #pragma unroll
    for (int kk = 0; kk < 2; ++kk)
      #pragma unroll
      for (int dt = 0; dt < 4; ++dt)
        vf[kk][dt] = *(const s16x8*)(cV + (dt * 16 + li) * 64 + ((((kk << 2) | g) ^ (li & 7)) << 3));

    softmax_pv(sH, vf, t == qbH, w, g, li, sPw, mH, lH, accH);
    if (doLo) softmax_pv(sL, vf, t == qbL, w, g, li, sPw, mL, lL, accL);
  }

  write_out(accL, lL, qbL, h, w, g, li, lane, sPw, out16);
  write_out(accH, lH, qbH, h, w, g, li, lane, sPw, out16);
}

// ---------------- O projection + residual ----------------
__global__ __launch_bounds__(256) void oproj_kernel(
    const short* __restrict__ ao, const short* __restrict__ wo,
    const float* __restrict__ resid, float* __restrict__ out) {
  __shared__ short sA[2 * 128 * 64];
  __shared__ short sB[2 * 128 * 64];
  const int cb = blockIdx.x, rb = blockIdx.y;
  f32x4 acc[4][4];
  const f32x4 z = {0.f, 0.f, 0.f, 0.f};
  #pragma unroll
  for (int m = 0; m < 4; ++m)
    #pragma unroll
    for (int n = 0; n < 4; ++n) acc[m][n] = z;

  gemm_core_128(ao + (int64_t)rb * 128 * HID, wo + (int64_t)cb * 128 * HID, sA, sB, acc);

  const int lane = threadIdx.x & 63;
  const int w = threadIdx.x >> 6, wr = w >> 1, wc = w & 1;
  const int g = lane >> 4, li = lane & 15;
  #pragma unroll
  for (int m = 0; m < 4; ++m) {
    #pragma unroll
    for (int n = 0; n < 4; ++n) {
      const int col = cb * 128 + wc * 64 + n * 16 + li;
      #pragma unroll
      for (int r = 0; r < 4; ++r) {
        const int row = rb * 128 + wr * 64 + m * 16 + g * 4 + r;
        out[(int64_t)row * HID + col] = acc[m][n][r] + resid[(int64_t)row * HID + col];
      }
    }
  }
}

extern "C" void kernel_launch(void* const* d_in, const int* in_sizes, int n_in,
                              void* d_out, int out_size, void* d_ws, size_t ws_size,
                              hipStream_t stream) {
  (void)in_sizes; (void)n_in; (void)out_size; (void)ws_size;
  const float* x      = (const float*)d_in[0];
  const float* norm_w = (const float*)d_in[2];
  const float* Wq     = (const float*)d_in[3];
  const float* Wk     = (const float*)d_in[4];
  const float* Wv     = (const float*)d_in[5];
  const float* Wo     = (const float*)d_in[6];
  const float* rc     = (const float*)d_in[7];
  const float* rs     = (const float*)d_in[8];
  float* out = (float*)d_out;

  char* ws = (char*)d_ws;
  short* wq16 = (short*)(ws);
  short* wk16 = (short*)(ws + 8388608);
  short* wv16 = (short*)(ws + 10485760);
  short* wo16 = (short*)(ws + 12582912);
  short* h16  = (short*)(ws + 20971520);
  short* q16  = (short*)(ws + 29360128);
  short* k16  = (short*)(ws + 37748736);
  short* vt16 = (short*)(ws + 39845888);
  short* ao16 = (short*)(ws + 41943040);

  convert_weights_kernel<<<10240, 256, 0, stream>>>(Wq, Wk, Wv, Wo, wq16, wk16, wv16, wo16);
  rmsnorm_kernel<<<L_SEQ, 256, 0, stream>>>(x, norm_w, h16);
  qkv_kernel<<<dim3(24, 16), 256, 0, stream>>>(h16, wq16, wk16, wv16, q16, k16, vt16, rc, rs);
  attn_kernel<<<dim3(16, NHEAD), 256, 0, stream>>>(q16, k16, vt16, ao16);
  oproj_kernel<<<dim3(16, 16), 256, 0, stream>>>(ao16, wo16, x, out);
}

// Round 9
// 142.754 us; speedup vs baseline: 1.5648x; 1.0055x over previous
//
#include <hip/hip_runtime.h>
#include <stdint.h>

#define L_SEQ 2048
#define HID   2048
#define NHEAD 32
#define NKV   8
#define HD    64
#define KVDIM 512
#define QSCALE 0.18033688f         /* log2(e)/8 folded into Q at projection */

typedef __attribute__((ext_vector_type(8))) short s16x8;
typedef __attribute__((ext_vector_type(4))) short s16x4;
typedef __attribute__((ext_vector_type(4))) float f32x4;

// native RNE f32->bf16 (v_cvt_pk_bf16_f32 on gfx950)
__device__ __forceinline__ short f2bf(float f) {
  __bf16 b = (__bf16)f;
  short s;
  __builtin_memcpy(&s, &b, 2);
  return s;
}

// async global->LDS, 16B/lane. Linear LDS dest + inverse-swizzled global
// source + swizzled read (rule #21).
__device__ __forceinline__ void gload16(const void* g, void* l) {
  __builtin_amdgcn_global_load_lds(
      (const __attribute__((address_space(1))) void*)g,
      (__attribute__((address_space(3))) void*)l, 16, 0, 0);
}

// ---------------- fused weight-convert + RMSNorm (one launch) ----------------
// blocks 0..2047: rmsnorm rows; blocks 2048..12287: f32->bf16 weight convert.
__global__ __launch_bounds__(256) void pre_kernel(
    const float* __restrict__ x, const float* __restrict__ w,
    const float* __restrict__ wq, const float* __restrict__ wk,
    const float* __restrict__ wv, const float* __restrict__ wo,
    short* __restrict__ h,
    short* __restrict__ owq, short* __restrict__ owk,
    short* __restrict__ owv, short* __restrict__ owo) {
  const int tid = threadIdx.x;
  if (blockIdx.x >= 2048) {
    int64_t e = ((int64_t)(blockIdx.x - 2048) * 256 + tid) * 4;
    const float* src; short* dst; int64_t o;
    if (e < 4194304)      { src = wq; dst = owq; o = e; }
    else if (e < 5242880) { src = wk; dst = owk; o = e - 4194304; }
    else if (e < 6291456) { src = wv; dst = owv; o = e - 5242880; }
    else                  { src = wo; dst = owo; o = e - 6291456; }
    f32x4 v = *(const f32x4*)(src + o);
    s16x4 b;
    b[0] = f2bf(v[0]); b[1] = f2bf(v[1]); b[2] = f2bf(v[2]); b[3] = f2bf(v[3]);
    *(s16x4*)(dst + o) = b;
    return;
  }
  const int row = blockIdx.x;
  const float* xr = x + (int64_t)row * HID + tid * 8;
  f32x4 a = *(const f32x4*)(xr);
  f32x4 b = *(const f32x4*)(xr + 4);
  float ss = a[0]*a[0]+a[1]*a[1]+a[2]*a[2]+a[3]*a[3]
           + b[0]*b[0]+b[1]*b[1]+b[2]*b[2]+b[3]*b[3];
  #pragma unroll
  for (int off = 1; off < 64; off <<= 1) ss += __shfl_xor(ss, off, 64);
  __shared__ float sred[4];
  if ((tid & 63) == 0) sred[tid >> 6] = ss;
  __syncthreads();
  const float scale = rsqrtf((sred[0]+sred[1]+sred[2]+sred[3]) * (1.0f/HID) + 1e-6f);
  const float* wp = w + tid * 8;
  f32x4 wa = *(const f32x4*)(wp);
  f32x4 wb = *(const f32x4*)(wp + 4);
  s16x8 o;
  o[0]=f2bf(a[0]*scale*wa[0]); o[1]=f2bf(a[1]*scale*wa[1]);
  o[2]=f2bf(a[2]*scale*wa[2]); o[3]=f2bf(a[3]*scale*wa[3]);
  o[4]=f2bf(b[0]*scale*wb[0]); o[5]=f2bf(b[1]*scale*wb[1]);
  o[6]=f2bf(b[2]*scale*wb[2]); o[7]=f2bf(b[3]*scale*wb[3]);
  *(s16x8*)(h + (int64_t)row * HID + tid * 8) = o;
}

// ---------------- GEMM core: C(128x128) = A(128xK) * B(128xK)^T, K=2048 ----
// Double-buffered 2-phase: issue next tile's global_load_lds right after the
// barrier, compute current tile under the in-flight loads.
__device__ __forceinline__ void gemm_core_128(
    const short* __restrict__ A, const short* __restrict__ B,
    short* sA, short* sB, f32x4 acc[4][4]) {
  const int tid = threadIdx.x;
  const int lane = tid & 63;
  const int w = tid >> 6, wr = w >> 1, wc = w & 1;
  const int g = lane >> 4, li = lane & 15;

  auto stage = [&](int k0, int buf) {
    #pragma unroll
    for (int i = 0; i < 4; ++i) {
      const int flat = i * 256 + tid;      // 0..1023 16B chunks
      const int row = flat >> 3, c8 = flat & 7;
      const int sc = c8 ^ (row & 7);       // inverse swizzle on source
      gload16(A + (int64_t)row * HID + k0 + sc * 8, sA + buf * 8192 + flat * 8);
      gload16(B + (int64_t)row * HID + k0 + sc * 8, sB + buf * 8192 + flat * 8);
    }
  };

  stage(0, 0);
  for (int k0 = 0; k0 < HID; k0 += 64) {
    const int cur = (k0 >> 6) & 1;
    __syncthreads();                       // cur loads landed; prev buf free
    if (k0 + 64 < HID) stage(k0 + 64, cur ^ 1);
    const short* cA = sA + cur * 8192;
    const short* cB = sB + cur * 8192;
    #pragma unroll
    for (int kk = 0; kk < 2; ++kk) {
      s16x8 af[4], bfr[4];
      const int chunk = (kk << 2) | g;
      #pragma unroll
      for (int m = 0; m < 4; ++m) {
        const int row = wr * 64 + m * 16 + li;
        af[m] = *(const s16x8*)(cA + row * 64 + ((chunk ^ (li & 7)) << 3));
      }
      #pragma unroll
      for (int n = 0; n < 4; ++n) {
        const int row = wc * 64 + n * 16 + li;
        bfr[n] = *(const s16x8*)(cB + row * 64 + ((chunk ^ (li & 7)) << 3));
      }
      #pragma unroll
      for (int m = 0; m < 4; ++m)
        #pragma unroll
        for (int n = 0; n < 4; ++n)
          acc[m][n] = __builtin_amdgcn_mfma_f32_16x16x32_bf16(af[m], bfr[n], acc[m][n], 0, 0, 0);
    }
  }
}

// ---------------- fused QKV projection + RoPE (+ V transpose) ----------------
// Q additionally pre-scaled by log2(e)/8 (folded into rope cos/sin) so the
// attention softmax runs in pure exp2 domain with no per-element fma.
__global__ __launch_bounds__(256) void qkv_kernel(
    const short* __restrict__ h16, const short* __restrict__ wq,
    const short* __restrict__ wk, const short* __restrict__ wv,
    short* __restrict__ qo, short* __restrict__ ko, short* __restrict__ vto,
    const float* __restrict__ rc, const float* __restrict__ rs) {
  __shared__ short sA[2 * 128 * 64];
  __shared__ short sB[2 * 128 * 64];
  const int cb = blockIdx.x, rb = blockIdx.y;
  const short* B; short* out; int colbase, mode; int64_t ldc;
  if (cb < 16)      { B = wq + (int64_t)cb * 128 * HID;        out = qo;  colbase = cb * 128;        mode = 0; ldc = HID;   }
  else if (cb < 20) { B = wk + (int64_t)(cb - 16) * 128 * HID; out = ko;  colbase = (cb - 16) * 128; mode = 0; ldc = KVDIM; }
  else              { B = wv + (int64_t)(cb - 20) * 128 * HID; out = vto; colbase = (cb - 20) * 128; mode = 1; ldc = L_SEQ; }
  const float rsc = (cb < 16) ? QSCALE : 1.0f;

  f32x4 acc[4][4];
  const f32x4 z = {0.f, 0.f, 0.f, 0.f};
  #pragma unroll
  for (int m = 0; m < 4; ++m)
    #pragma unroll
    for (int n = 0; n < 4; ++n) acc[m][n] = z;

  gemm_core_128(h16 + (int64_t)rb * 128 * HID, B, sA, sB, acc);

  const int lane = threadIdx.x & 63;
  const int w = threadIdx.x >> 6, wr = w >> 1, wc = w & 1;
  const int g = lane >> 4, li = lane & 15;

  if (mode == 0) {
    #pragma unroll
    for (int m = 0; m < 4; ++m) {
      #pragma unroll
      for (int n = 0; n < 4; ++n) {
        const int col = colbase + wc * 64 + n * 16 + li;
        const int d2 = col & 62;
        #pragma unroll
        for (int r = 0; r < 4; ++r) {
          const int row = rb * 128 + wr * 64 + m * 16 + g * 4 + r;
          const float c = rc[row * 64 + d2] * rsc;
          const float s = rs[row * 64 + d2] * rsc;
          const float v0 = acc[m][n][r];
          const float pr = __shfl_xor(v0, 1, 64);
          const float o = (lane & 1) ? (v0 * c + pr * s) : (v0 * c - pr * s);
          out[(int64_t)row * ldc + col] = f2bf(o);
        }
      }
    }
  } else {
    #pragma unroll
    for (int m = 0; m < 4; ++m) {
      #pragma unroll
      for (int n = 0; n < 4; ++n) {
        const int col = colbase + wc * 64 + n * 16 + li;
        const int row0 = rb * 128 + wr * 64 + m * 16 + g * 4;
        s16x4 pk;
        pk[0] = f2bf(acc[m][n][0]); pk[1] = f2bf(acc[m][n][1]);
        pk[2] = f2bf(acc[m][n][2]); pk[3] = f2bf(acc[m][n][3]);
        *(s16x4*)(out + (int64_t)col * L_SEQ + row0) = pk;
      }
    }
  }
}

// ---------------- causal GQA flash attention ----------------
// R8 structure + T4: 3-buffer K/V staging with counted vmcnt across raw
// s_barrier — stage(t+1) stays IN FLIGHT across the barrier (never drained
// mid-loop). Paired q-blocks, swapped QK^T, exp2-domain softmax (Q carries
// log2e/8), defer-max (P <= 2^8), setprio around MFMA. Deterministic.
__device__ __forceinline__ void softmax_pv(
    f32x4 s[4], const s16x8 vf[2][4], bool diag,
    int w, int g, int li, short* sPw,
    float& m, float& l, f32x4 acc[4]) {
  if (diag) {
    const int ql = w * 16 + li;
    #pragma unroll
    for (int n = 0; n < 4; ++n)
      #pragma unroll
      for (int r = 0; r < 4; ++r)
        if (n * 16 + g * 4 + r > ql) s[n][r] = -1e30f;
  }
  float mx = fmaxf(fmaxf(s[0][0], s[0][1]), fmaxf(s[0][2], s[0][3]));
  #pragma unroll
  for (int n = 1; n < 4; ++n)
    mx = fmaxf(mx, fmaxf(fmaxf(s[n][0], s[n][1]), fmaxf(s[n][2], s[n][3])));
  mx = fmaxf(mx, __shfl_xor(mx, 16, 64));
  mx = fmaxf(mx, __shfl_xor(mx, 32, 64));
  if (__any(mx > m + 8.0f)) {              // rare after early tiles
    const float mn = fmaxf(m, mx);
    const float al = __builtin_amdgcn_exp2f(m - mn);
    m = mn;
    l *= al;
    #pragma unroll
    for (int dt = 0; dt < 4; ++dt)
      #pragma unroll
      for (int r = 0; r < 4; ++r) acc[dt][r] *= al;
  }
  float ps = 0.f;
  #pragma unroll
  for (int n = 0; n < 4; ++n) {
    s16x4 pk;
    #pragma unroll
    for (int r = 0; r < 4; ++r) {
      const float p = __builtin_amdgcn_exp2f(s[n][r] - m);
      pk[r] = f2bf(p);
      ps += p;
    }
    *(s16x4*)(sPw + li * 64 + (((n * 2 + (g >> 1)) ^ (li & 7)) << 3) + (g & 1) * 4) = pk;
  }
  ps += __shfl_xor(ps, 16, 64);
  ps += __shfl_xor(ps, 32, 64);
  l += ps;
  // PV: O^T[d][q] += V^T[d][kv] * P^T[kv][q]
  #pragma unroll
  for (int kk = 0; kk < 2; ++kk) {
    s16x8 pf = *(const s16x8*)(sPw + li * 64 + (((kk * 4 + g) ^ (li & 7)) << 3));
    __builtin_amdgcn_s_setprio(1);
    #pragma unroll
    for (int dt = 0; dt < 4; ++dt)
      acc[dt] = __builtin_amdgcn_mfma_f32_16x16x32_bf16(vf[kk][dt], pf, acc[dt], 0, 0, 0);
    __builtin_amdgcn_s_setprio(0);
  }
}

__device__ __forceinline__ void write_out(
    const f32x4 acc[4], float l, int qb, int h, int w, int g, int li, int lane,
    short* sPw, short* __restrict__ out16) {
  const float rl = 1.0f / l;
  #pragma unroll
  for (int n2 = 0; n2 < 4; ++n2) {
    s16x4 o;
    #pragma unroll
    for (int r = 0; r < 4; ++r) o[r] = f2bf(acc[n2][r] * rl);
    *(s16x4*)(sPw + li * 64 + (((n2 * 2 + (g >> 1)) ^ (li & 7)) << 3) + (g & 1) * 4) = o;
  }
  #pragma unroll
  for (int half = 0; half < 2; ++half) {
    const int chunk = half * 64 + lane;
    const int q = chunk >> 3, c = chunk & 7;
    s16x8 v = *(const s16x8*)(sPw + q * 64 + ((c ^ (q & 7)) << 3));
    *(s16x8*)(out16 + (int64_t)(qb * 64 + w * 16 + q) * HID + h * 64 + c * 8) = v;
  }
}

__global__ __launch_bounds__(256) void attn_kernel(
    const short* __restrict__ q16, const short* __restrict__ k16,
    const short* __restrict__ vt16, short* __restrict__ out16) {
  __shared__ short sK[3 * 64 * 64];       // 3-deep K dbuf (24 KB)
  __shared__ short sV[3 * 64 * 64];       // 3-deep V^T dbuf (24 KB)
  __shared__ short sP[4][16 * 64];        // per-wave P^T relayout / out transpose
  const int pi = blockIdx.x, h = blockIdx.y, kvh = h >> 2;
  const int qbL = pi, qbH = 31 - pi;
  const int tid = threadIdx.x, lane = tid & 63, w = tid >> 6;
  const int g = lane >> 4, li = lane & 15;
  short* sPw = &sP[w][0];

  s16x8 qfL[2], qfH[2];
  {
    const int qrL = qbL * 64 + w * 16 + li;
    const int qrH = qbH * 64 + w * 16 + li;
    #pragma unroll
    for (int kk = 0; kk < 2; ++kk) {
      qfL[kk] = *(const s16x8*)(q16 + (int64_t)qrL * HID + h * 64 + kk * 32 + g * 8);
      qfH[kk] = *(const s16x8*)(q16 + (int64_t)qrH * HID + h * 64 + kk * 32 + g * 8);
    }
  }

  f32x4 accL[4], accH[4];
  const f32x4 z = {0.f, 0.f, 0.f, 0.f};
  #pragma unroll
  for (int n = 0; n < 4; ++n) { accL[n] = z; accH[n] = z; }
  float mL = -1e30f, lL = 0.f, mH = -1e30f, lH = 0.f;

  auto stage = [&](int t, int buf) {
    const int kv0 = t * 64;
    #pragma unroll
    for (int i = 0; i < 2; ++i) {
      const int flat = i * 256 + tid;      // 0..511 16B chunks
      const int row = flat >> 3, c8 = flat & 7;
      const int sc = c8 ^ (row & 7);
      gload16(k16 + (int64_t)(kv0 + row) * KVDIM + kvh * 64 + sc * 8,
              sK + buf * 4096 + flat * 8);
      gload16(vt16 + (int64_t)(kvh * 64 + row) * L_SEQ + kv0 + sc * 8,
              sV + buf * 4096 + flat * 8);
    }
  };

  stage(0, 0);                             // 2 vm-ops/wave
  stage(1, 1);                             // 2 more in flight
  int cur = 0;
  for (int t = 0; t <= qbH; ++t) {
    // wait ONLY for stage(t) (2 oldest retire; stage(t+1)'s 2 stay in flight)
    if (t < qbH) asm volatile("s_waitcnt vmcnt(2)" ::: "memory");
    else         asm volatile("s_waitcnt vmcnt(0)" ::: "memory");
    __builtin_amdgcn_sched_barrier(0);
    __builtin_amdgcn_s_barrier();          // all waves: buf cur fully written,
    __builtin_amdgcn_sched_barrier(0);     // buf (t+2)%3 fully consumed
    if (t + 2 <= qbH) stage(t + 2, cur == 0 ? 2 : cur - 1);
    const short* cK = sK + cur * 4096;
    const short* cV = sV + cur * 4096;

    // shared K fragments (A-operand: row = kv)
    s16x8 kf[2][4];
    #pragma unroll
    for (int kk = 0; kk < 2; ++kk)
      #pragma unroll
      for (int n = 0; n < 4; ++n)
        kf[kk][n] = *(const s16x8*)(cK + (n * 16 + li) * 64 + ((((kk << 2) | g) ^ (li & 7)) << 3));

    const bool doLo = (t <= qbL);
    f32x4 sH[4], sL[4];
    #pragma unroll
    for (int n = 0; n < 4; ++n) sH[n] = z;
    __builtin_amdgcn_s_setprio(1);
    #pragma unroll
    for (int kk = 0; kk < 2; ++kk)
      #pragma unroll
      for (int n = 0; n < 4; ++n)
        sH[n] = __builtin_amdgcn_mfma_f32_16x16x32_bf16(kf[kk][n], qfH[kk], sH[n], 0, 0, 0);
    __builtin_amdgcn_s_setprio(0);
    if (doLo) {
      #pragma unroll
      for (int n = 0; n < 4; ++n) sL[n] = z;
      __builtin_amdgcn_s_setprio(1);
      #pragma unroll
      for (int kk = 0; kk < 2; ++kk)
        #pragma unroll
        for (int n = 0; n < 4; ++n)
          sL[n] = __builtin_amdgcn_mfma_f32_16x16x32_bf16(kf[kk][n], qfL[kk], sL[n], 0, 0, 0);
      __builtin_amdgcn_s_setprio(0);
    }

    // shared V^T fragments (A-operand: row = d)
    s16x8 vf[2][4];
    #pragma unroll
    for (int kk = 0; kk < 2; ++kk)
      #pragma unroll
      for (int dt = 0; dt < 4; ++dt)
        vf[kk][dt] = *(const s16x8*)(cV + (dt * 16 + li) * 64 + ((((kk << 2) | g) ^ (li & 7)) << 3));

    softmax_pv(sH, vf, t == qbH, w, g, li, sPw, mH, lH, accH);
    if (doLo) softmax_pv(sL, vf, t == qbL, w, g, li, sPw, mL, lL, accL);

    cur = (cur == 2) ? 0 : cur + 1;
  }

  write_out(accL, lL, qbL, h, w, g, li, lane, sPw, out16);
  write_out(accH, lH, qbH, h, w, g, li, lane, sPw, out16);
}

// ---------------- O projection + residual ----------------
__global__ __launch_bounds__(256) void oproj_kernel(
    const short* __restrict__ ao, const short* __restrict__ wo,
    const float* __restrict__ resid, float* __restrict__ out) {
  __shared__ short sA[2 * 128 * 64];
  __shared__ short sB[2 * 128 * 64];
  const int cb = blockIdx.x, rb = blockIdx.y;
  f32x4 acc[4][4];
  const f32x4 z = {0.f, 0.f, 0.f, 0.f};
  #pragma unroll
  for (int m = 0; m < 4; ++m)
    #pragma unroll
    for (int n = 0; n < 4; ++n) acc[m][n] = z;

  gemm_core_128(ao + (int64_t)rb * 128 * HID, wo + (int64_t)cb * 128 * HID, sA, sB, acc);

  const int lane = threadIdx.x & 63;
  const int w = threadIdx.x >> 6, wr = w >> 1, wc = w & 1;
  const int g = lane >> 4, li = lane & 15;
  #pragma unroll
  for (int m = 0; m < 4; ++m) {
    #pragma unroll
    for (int n = 0; n < 4; ++n) {
      const int col = cb * 128 + wc * 64 + n * 16 + li;
      #pragma unroll
      for (int r = 0; r < 4; ++r) {
        const int row = rb * 128 + wr * 64 + m * 16 + g * 4 + r;
        out[(int64_t)row * HID + col] = acc[m][n][r] + resid[(int64_t)row * HID + col];
      }
    }
  }
}

extern "C" void kernel_launch(void* const* d_in, const int* in_sizes, int n_in,
                              void* d_out, int out_size, void* d_ws, size_t ws_size,
                              hipStream_t stream) {
  (void)in_sizes; (void)n_in; (void)out_size; (void)ws_size;
  const float* x      = (const float*)d_in[0];
  const float* norm_w = (const float*)d_in[2];
  const float* Wq     = (const float*)d_in[3];
  const float* Wk     = (const float*)d_in[4];
  const float* Wv     = (const float*)d_in[5];
  const float* Wo     = (const float*)d_in[6];
  const float* rc     = (const float*)d_in[7];
  const float* rs     = (const float*)d_in[8];
  float* out = (float*)d_out;

  char* ws = (char*)d_ws;
  short* wq16 = (short*)(ws);
  short* wk16 = (short*)(ws + 8388608);
  short* wv16 = (short*)(ws + 10485760);
  short* wo16 = (short*)(ws + 12582912);
  short* h16  = (short*)(ws + 20971520);
  short* q16  = (short*)(ws + 29360128);
  short* k16  = (short*)(ws + 37748736);
  short* vt16 = (short*)(ws + 39845888);
  short* ao16 = (short*)(ws + 41943040);

  pre_kernel<<<12288, 256, 0, stream>>>(x, norm_w, Wq, Wk, Wv, Wo,
                                        h16, wq16, wk16, wv16, wo16);
  qkv_kernel<<<dim3(24, 16), 256, 0, stream>>>(h16, wq16, wk16, wv16, q16, k16, vt16, rc, rs);
  attn_kernel<<<dim3(16, NHEAD), 256, 0, stream>>>(q16, k16, vt16, ao16);
  oproj_kernel<<<dim3(16, 16), 256, 0, stream>>>(ao16, wo16, x, out);
}

// Round 10
// 127.259 us; speedup vs baseline: 1.7553x; 1.1218x over previous
//
#include <hip/hip_runtime.h>
#include <stdint.h>

#define L_SEQ 2048
#define HID   2048
#define NHEAD 32
#define NKV   8
#define HD    64
#define KVDIM 512
#define QSCALE 0.18033688f         /* log2(e)/8 folded into Q at projection */

typedef __attribute__((ext_vector_type(8))) short s16x8;
typedef __attribute__((ext_vector_type(4))) short s16x4;
typedef __attribute__((ext_vector_type(4))) float f32x4;

// native RNE f32->bf16 (v_cvt_pk_bf16_f32 on gfx950)
__device__ __forceinline__ short f2bf(float f) {
  __bf16 b = (__bf16)f;
  short s;
  __builtin_memcpy(&s, &b, 2);
  return s;
}

// async global->LDS, 16B/lane. Linear LDS dest + inverse-swizzled global
// source + swizzled read (rule #21).
__device__ __forceinline__ void gload16(const void* g, void* l) {
  __builtin_amdgcn_global_load_lds(
      (const __attribute__((address_space(1))) void*)g,
      (__attribute__((address_space(3))) void*)l, 16, 0, 0);
}

// ---------------- fused weight-convert + RMSNorm (one launch) ----------------
__global__ __launch_bounds__(256) void pre_kernel(
    const float* __restrict__ x, const float* __restrict__ w,
    const float* __restrict__ wq, const float* __restrict__ wk,
    const float* __restrict__ wv, const float* __restrict__ wo,
    short* __restrict__ h,
    short* __restrict__ owq, short* __restrict__ owk,
    short* __restrict__ owv, short* __restrict__ owo) {
  const int tid = threadIdx.x;
  if (blockIdx.x >= 2048) {
    int64_t e = ((int64_t)(blockIdx.x - 2048) * 256 + tid) * 4;
    const float* src; short* dst; int64_t o;
    if (e < 4194304)      { src = wq; dst = owq; o = e; }
    else if (e < 5242880) { src = wk; dst = owk; o = e - 4194304; }
    else if (e < 6291456) { src = wv; dst = owv; o = e - 5242880; }
    else                  { src = wo; dst = owo; o = e - 6291456; }
    f32x4 v = *(const f32x4*)(src + o);
    s16x4 b;
    b[0] = f2bf(v[0]); b[1] = f2bf(v[1]); b[2] = f2bf(v[2]); b[3] = f2bf(v[3]);
    *(s16x4*)(dst + o) = b;
    return;
  }
  const int row = blockIdx.x;
  const float* xr = x + (int64_t)row * HID + tid * 8;
  f32x4 a = *(const f32x4*)(xr);
  f32x4 b = *(const f32x4*)(xr + 4);
  float ss = a[0]*a[0]+a[1]*a[1]+a[2]*a[2]+a[3]*a[3]
           + b[0]*b[0]+b[1]*b[1]+b[2]*b[2]+b[3]*b[3];
  #pragma unroll
  for (int off = 1; off < 64; off <<= 1) ss += __shfl_xor(ss, off, 64);
  __shared__ float sred[4];
  if ((tid & 63) == 0) sred[tid >> 6] = ss;
  __syncthreads();
  const float scale = rsqrtf((sred[0]+sred[1]+sred[2]+sred[3]) * (1.0f/HID) + 1e-6f);
  const float* wp = w + tid * 8;
  f32x4 wa = *(const f32x4*)(wp);
  f32x4 wb = *(const f32x4*)(wp + 4);
  s16x8 o;
  o[0]=f2bf(a[0]*scale*wa[0]); o[1]=f2bf(a[1]*scale*wa[1]);
  o[2]=f2bf(a[2]*scale*wa[2]); o[3]=f2bf(a[3]*scale*wa[3]);
  o[4]=f2bf(b[0]*scale*wb[0]); o[5]=f2bf(b[1]*scale*wb[1]);
  o[6]=f2bf(b[2]*scale*wb[2]); o[7]=f2bf(b[3]*scale*wb[3]);
  *(s16x8*)(h + (int64_t)row * HID + tid * 8) = o;
}

// ---------------- GEMM core: C(128x64) = A(128xK) * B(64xK)^T, K=2048 ----
// Same verified structure as the 128x128 core, N-frags = 2. Smaller tiles ->
// 2-3 blocks/CU (grid was the occupancy cap at 128x128).
__device__ __forceinline__ void gemm_core_128x64(
    const short* __restrict__ A, const short* __restrict__ B,
    short* sA, short* sB, f32x4 acc[4][2]) {
  const int tid = threadIdx.x;
  const int lane = tid & 63;
  const int w = tid >> 6, wr = w >> 1, wc = w & 1;
  const int g = lane >> 4, li = lane & 15;

  auto stage = [&](int k0, int buf) {
    #pragma unroll
    for (int i = 0; i < 4; ++i) {
      const int flat = i * 256 + tid;      // A: 1024 16B chunks
      const int row = flat >> 3, c8 = flat & 7;
      const int sc = c8 ^ (row & 7);
      gload16(A + (int64_t)row * HID + k0 + sc * 8, sA + buf * 8192 + flat * 8);
    }
    #pragma unroll
    for (int i = 0; i < 2; ++i) {
      const int flat = i * 256 + tid;      // B: 512 16B chunks
      const int row = flat >> 3, c8 = flat & 7;
      const int sc = c8 ^ (row & 7);
      gload16(B + (int64_t)row * HID + k0 + sc * 8, sB + buf * 4096 + flat * 8);
    }
  };

  stage(0, 0);
  for (int k0 = 0; k0 < HID; k0 += 64) {
    const int cur = (k0 >> 6) & 1;
    __syncthreads();                       // cur loads landed; prev buf free
    if (k0 + 64 < HID) stage(k0 + 64, cur ^ 1);
    const short* cA = sA + cur * 8192;
    const short* cB = sB + cur * 4096;
    #pragma unroll
    for (int kk = 0; kk < 2; ++kk) {
      s16x8 af[4], bfr[2];
      const int chunk = (kk << 2) | g;
      #pragma unroll
      for (int m = 0; m < 4; ++m) {
        const int row = wr * 64 + m * 16 + li;
        af[m] = *(const s16x8*)(cA + row * 64 + ((chunk ^ (li & 7)) << 3));
      }
      #pragma unroll
      for (int n = 0; n < 2; ++n) {
        const int row = wc * 32 + n * 16 + li;
        bfr[n] = *(const s16x8*)(cB + row * 64 + ((chunk ^ (li & 7)) << 3));
      }
      __builtin_amdgcn_s_setprio(1);
      #pragma unroll
      for (int m = 0; m < 4; ++m)
        #pragma unroll
        for (int n = 0; n < 2; ++n)
          acc[m][n] = __builtin_amdgcn_mfma_f32_16x16x32_bf16(af[m], bfr[n], acc[m][n], 0, 0, 0);
      __builtin_amdgcn_s_setprio(0);
    }
  }
}

// ---------------- fused QKV projection + RoPE (+ V transpose) ----------------
// grid x: 0..31 Q | 32..39 K | 40..47 V (64-col blocks); y: 16 row-blocks.
__global__ __launch_bounds__(256) void qkv_kernel(
    const short* __restrict__ h16, const short* __restrict__ wq,
    const short* __restrict__ wk, const short* __restrict__ wv,
    short* __restrict__ qo, short* __restrict__ ko, short* __restrict__ vto,
    const float* __restrict__ rc, const float* __restrict__ rs) {
  __shared__ short sA[2 * 128 * 64];       // 32 KB
  __shared__ short sB[2 * 64 * 64];        // 16 KB
  const int cb = blockIdx.x, rb = blockIdx.y;
  const short* B; short* out; int colbase, mode; int64_t ldc;
  if (cb < 32)      { B = wq + (int64_t)cb * 64 * HID;        out = qo;  colbase = cb * 64;        mode = 0; ldc = HID;   }
  else if (cb < 40) { B = wk + (int64_t)(cb - 32) * 64 * HID; out = ko;  colbase = (cb - 32) * 64; mode = 0; ldc = KVDIM; }
  else              { B = wv + (int64_t)(cb - 40) * 64 * HID; out = vto; colbase = (cb - 40) * 64; mode = 1; ldc = L_SEQ; }
  const float rsc = (cb < 32) ? QSCALE : 1.0f;

  f32x4 acc[4][2];
  const f32x4 z = {0.f, 0.f, 0.f, 0.f};
  #pragma unroll
  for (int m = 0; m < 4; ++m)
    #pragma unroll
    for (int n = 0; n < 2; ++n) acc[m][n] = z;

  gemm_core_128x64(h16 + (int64_t)rb * 128 * HID, B, sA, sB, acc);

  const int lane = threadIdx.x & 63;
  const int w = threadIdx.x >> 6, wr = w >> 1, wc = w & 1;
  const int g = lane >> 4, li = lane & 15;

  if (mode == 0) {
    #pragma unroll
    for (int m = 0; m < 4; ++m) {
      #pragma unroll
      for (int n = 0; n < 2; ++n) {
        const int col = colbase + wc * 32 + n * 16 + li;
        const int d2 = col & 62;
        #pragma unroll
        for (int r = 0; r < 4; ++r) {
          const int row = rb * 128 + wr * 64 + m * 16 + g * 4 + r;
          const float c = rc[row * 64 + d2] * rsc;
          const float s = rs[row * 64 + d2] * rsc;
          const float v0 = acc[m][n][r];
          const float pr = __shfl_xor(v0, 1, 64);
          const float o = (lane & 1) ? (v0 * c + pr * s) : (v0 * c - pr * s);
          out[(int64_t)row * ldc + col] = f2bf(o);
        }
      }
    }
  } else {
    #pragma unroll
    for (int m = 0; m < 4; ++m) {
      #pragma unroll
      for (int n = 0; n < 2; ++n) {
        const int col = colbase + wc * 32 + n * 16 + li;
        const int row0 = rb * 128 + wr * 64 + m * 16 + g * 4;
        s16x4 pk;
        pk[0] = f2bf(acc[m][n][0]); pk[1] = f2bf(acc[m][n][1]);
        pk[2] = f2bf(acc[m][n][2]); pk[3] = f2bf(acc[m][n][3]);
        *(s16x4*)(out + (int64_t)col * L_SEQ + row0) = pk;
      }
    }
  }
}

// ---------------- causal GQA flash attention (8-wave paired blocks) ----------
// Block = (pair pi, head h), 512 threads: waves 0-3 run stream qbL = pi,
// waves 4-7 run stream qbH = 31-pi, sharing one 2-buffer K/V staging ->
// 16 waves/CU (was 8). Per-wave single-stream swapped QK^T, exp2 softmax
// (Q carries log2e/8), defer-max, setprio. Deterministic.
__global__ __launch_bounds__(512, 4) void attn_kernel(
    const short* __restrict__ q16, const short* __restrict__ k16,
    const short* __restrict__ vt16, short* __restrict__ out16) {
  __shared__ short sK[2 * 64 * 64];       // 16 KB
  __shared__ short sV[2 * 64 * 64];       // 16 KB  (V^T tile: [d][kv])
  __shared__ short sP[8][16 * 64];        // 16 KB  per-wave P^T / out transpose
  const int pi = blockIdx.x, h = blockIdx.y, kvh = h >> 2;
  const int qbL = pi, qbH = 31 - pi;
  const int tid = threadIdx.x, lane = tid & 63, w = tid >> 6, wl = w & 3;
  const int g = lane >> 4, li = lane & 15;
  const int myqb = (w < 4) ? qbL : qbH;
  short* sPw = &sP[w][0];

  s16x8 qf[2];
  {
    const int qr = myqb * 64 + wl * 16 + li;
    #pragma unroll
    for (int kk = 0; kk < 2; ++kk)
      qf[kk] = *(const s16x8*)(q16 + (int64_t)qr * HID + h * 64 + kk * 32 + g * 8);
  }

  f32x4 acc[4];
  const f32x4 z = {0.f, 0.f, 0.f, 0.f};
  #pragma unroll
  for (int n = 0; n < 4; ++n) acc[n] = z;
  float m = -1e30f, l = 0.f;

  auto stage = [&](int t, int buf) {
    const int kv0 = t * 64;
    const int row = tid >> 3, c8 = tid & 7;   // tid 0..511 -> 512 chunks each
    const int sc = c8 ^ (row & 7);
    gload16(k16 + (int64_t)(kv0 + row) * KVDIM + kvh * 64 + sc * 8,
            sK + buf * 4096 + tid * 8);
    gload16(vt16 + (int64_t)(kvh * 64 + row) * L_SEQ + kv0 + sc * 8,
            sV + buf * 4096 + tid * 8);
  };

  stage(0, 0);
  for (int t = 0; t <= qbH; ++t) {
    const int cur = t & 1;
    __syncthreads();                       // cur tile landed; prev buf free
    if (t < qbH) stage(t + 1, cur ^ 1);
    if (w >= 4 || t <= qbL) {
      const short* cK = sK + cur * 4096;
      const short* cV = sV + cur * 4096;

      // S^T = K * Q  (C cols = q = li, rows = kv)
      s16x8 kf[2][4];
      #pragma unroll
      for (int kk = 0; kk < 2; ++kk)
        #pragma unroll
        for (int n = 0; n < 4; ++n)
          kf[kk][n] = *(const s16x8*)(cK + (n * 16 + li) * 64 + ((((kk << 2) | g) ^ (li & 7)) << 3));
      f32x4 s[4];
      #pragma unroll
      for (int n = 0; n < 4; ++n) s[n] = z;
      __builtin_amdgcn_s_setprio(1);
      #pragma unroll
      for (int kk = 0; kk < 2; ++kk)
        #pragma unroll
        for (int n = 0; n < 4; ++n)
          s[n] = __builtin_amdgcn_mfma_f32_16x16x32_bf16(kf[kk][n], qf[kk], s[n], 0, 0, 0);
      __builtin_amdgcn_s_setprio(0);

      // causal mask on diagonal tile
      if (t == myqb) {
        const int ql = wl * 16 + li;
        #pragma unroll
        for (int n = 0; n < 4; ++n)
          #pragma unroll
          for (int r = 0; r < 4; ++r)
            if (n * 16 + g * 4 + r > ql) s[n][r] = -1e30f;
      }

      // online softmax (exp2 domain; Q pre-scaled), defer-max
      float mx = fmaxf(fmaxf(s[0][0], s[0][1]), fmaxf(s[0][2], s[0][3]));
      #pragma unroll
      for (int n = 1; n < 4; ++n)
        mx = fmaxf(mx, fmaxf(fmaxf(s[n][0], s[n][1]), fmaxf(s[n][2], s[n][3])));
      mx = fmaxf(mx, __shfl_xor(mx, 16, 64));
      mx = fmaxf(mx, __shfl_xor(mx, 32, 64));
      if (__any(mx > m + 8.0f)) {
        const float mn = fmaxf(m, mx);
        const float al = __builtin_amdgcn_exp2f(m - mn);
        m = mn;
        l *= al;
        #pragma unroll
        for (int dt = 0; dt < 4; ++dt)
          #pragma unroll
          for (int r = 0; r < 4; ++r) acc[dt][r] *= al;
      }
      float ps = 0.f;
      #pragma unroll
      for (int n = 0; n < 4; ++n) {
        s16x4 pk;
        #pragma unroll
        for (int r = 0; r < 4; ++r) {
          const float p = __builtin_amdgcn_exp2f(s[n][r] - m);
          pk[r] = f2bf(p);
          ps += p;
        }
        *(s16x4*)(sPw + li * 64 + (((n * 2 + (g >> 1)) ^ (li & 7)) << 3) + (g & 1) * 4) = pk;
      }
      ps += __shfl_xor(ps, 16, 64);
      ps += __shfl_xor(ps, 32, 64);
      l += ps;

      // O^T[d][q] += V^T[d][kv] * P^T[kv][q]
      s16x8 vf[2][4];
      #pragma unroll
      for (int kk = 0; kk < 2; ++kk)
        #pragma unroll
        for (int dt = 0; dt < 4; ++dt)
          vf[kk][dt] = *(const s16x8*)(cV + (dt * 16 + li) * 64 + ((((kk << 2) | g) ^ (li & 7)) << 3));
      #pragma unroll
      for (int kk = 0; kk < 2; ++kk) {
        s16x8 pf = *(const s16x8*)(sPw + li * 64 + (((kk * 4 + g) ^ (li & 7)) << 3));
        __builtin_amdgcn_s_setprio(1);
        #pragma unroll
        for (int dt = 0; dt < 4; ++dt)
          acc[dt] = __builtin_amdgcn_mfma_f32_16x16x32_bf16(vf[kk][dt], pf, acc[dt], 0, 0, 0);
        __builtin_amdgcn_s_setprio(0);
      }
    }
  }

  // normalize, per-wave transpose via sPw, coalesced 16B stores
  const float rl = 1.0f / l;
  #pragma unroll
  for (int n2 = 0; n2 < 4; ++n2) {
    s16x4 o;
    #pragma unroll
    for (int r = 0; r < 4; ++r) o[r] = f2bf(acc[n2][r] * rl);
    *(s16x4*)(sPw + li * 64 + (((n2 * 2 + (g >> 1)) ^ (li & 7)) << 3) + (g & 1) * 4) = o;
  }
  #pragma unroll
  for (int half = 0; half < 2; ++half) {
    const int chunk = half * 64 + lane;
    const int q = chunk >> 3, c = chunk & 7;
    s16x8 v = *(const s16x8*)(sPw + q * 64 + ((c ^ (q & 7)) << 3));
    *(s16x8*)(out16 + (int64_t)(myqb * 64 + wl * 16 + q) * HID + h * 64 + c * 8) = v;
  }
}

// ---------------- O projection + residual ----------------
__global__ __launch_bounds__(256) void oproj_kernel(
    const short* __restrict__ ao, const short* __restrict__ wo,
    const float* __restrict__ resid, float* __restrict__ out) {
  __shared__ short sA[2 * 128 * 64];
  __shared__ short sB[2 * 64 * 64];
  const int cb = blockIdx.x, rb = blockIdx.y;
  f32x4 acc[4][2];
  const f32x4 z = {0.f, 0.f, 0.f, 0.f};
  #pragma unroll
  for (int m = 0; m < 4; ++m)
    #pragma unroll
    for (int n = 0; n < 2; ++n) acc[m][n] = z;

  gemm_core_128x64(ao + (int64_t)rb * 128 * HID, wo + (int64_t)cb * 64 * HID, sA, sB, acc);

  const int lane = threadIdx.x & 63;
  const int w = threadIdx.x >> 6, wr = w >> 1, wc = w & 1;
  const int g = lane >> 4, li = lane & 15;
  #pragma unroll
  for (int m = 0; m < 4; ++m) {
    #pragma unroll
    for (int n = 0; n < 2; ++n) {
      const int col = cb * 64 + wc * 32 + n * 16 + li;
      #pragma unroll
      for (int r = 0; r < 4; ++r) {
        const int row = rb * 128 + wr * 64 + m * 16 + g * 4 + r;
        out[(int64_t)row * HID + col] = acc[m][n][r] + resid[(int64_t)row * HID + col];
      }
    }
  }
}

extern "C" void kernel_launch(void* const* d_in, const int* in_sizes, int n_in,
                              void* d_out, int out_size, void* d_ws, size_t ws_size,
                              hipStream_t stream) {
  (void)in_sizes; (void)n_in; (void)out_size; (void)ws_size;
  const float* x      = (const float*)d_in[0];
  const float* norm_w = (const float*)d_in[2];
  const float* Wq     = (const float*)d_in[3];
  const float* Wk     = (const float*)d_in[4];
  const float* Wv     = (const float*)d_in[5];
  const float* Wo     = (const float*)d_in[6];
  const float* rc     = (const float*)d_in[7];
  const float* rs     = (const float*)d_in[8];
  float* out = (float*)d_out;

  char* ws = (char*)d_ws;
  short* wq16 = (short*)(ws);
  short* wk16 = (short*)(ws + 8388608);
  short* wv16 = (short*)(ws + 10485760);
  short* wo16 = (short*)(ws + 12582912);
  short* h16  = (short*)(ws + 20971520);
  short* q16  = (short*)(ws + 29360128);
  short* k16  = (short*)(ws + 37748736);
  short* vt16 = (short*)(ws + 39845888);
  short* ao16 = (short*)(ws + 41943040);

  pre_kernel<<<12288, 256, 0, stream>>>(x, norm_w, Wq, Wk, Wv, Wo,
                                        h16, wq16, wk16, wv16, wo16);
  qkv_kernel<<<dim3(48, 16), 256, 0, stream>>>(h16, wq16, wk16, wv16, q16, k16, vt16, rc, rs);
  attn_kernel<<<dim3(16, NHEAD), 512, 0, stream>>>(q16, k16, vt16, ao16);
  oproj_kernel<<<dim3(32, 16), 256, 0, stream>>>(ao16, wo16, x, out);
}